// Round 17
// baseline (324.697 us; speedup 1.0000x reference)
//
#include <hip/hip_runtime.h>

#define NA   16384
#define NE   524288
#define NM   256
#define FF   4800
#define FR   2688   // folded K: 55 pair-blocks * 48 + 48 pad ; f' = b*48 + l*16 + qi*4 + pi
#define HH   512
#define NMX  10
#define NSPH 9

typedef __bf16 bf16x8 __attribute__((ext_vector_type(8)));
typedef float  f32x4  __attribute__((ext_vector_type(4)));
typedef unsigned short u16x8 __attribute__((ext_vector_type(8)));
typedef unsigned short u16x4 __attribute__((ext_vector_type(4)));

__constant__ int g_ka[22] = {0, 1,1,1,2,2,3, 4,4,4,4,4, 5,5,5,5, 6,6,6, 7,7, 8};
__constant__ int g_kb[22] = {0, 1,2,3,2,3,3, 4,5,6,7,8, 5,6,7,8, 6,7,8, 7,8, 8};

__device__ inline unsigned short f2bf(float x){
  return __builtin_bit_cast(unsigned short, (__bf16)x);
}
__device__ inline float bf2f(unsigned short h){
  unsigned int u = ((unsigned int)h) << 16;
  return __builtin_bit_cast(float, u);
}
__device__ inline void atomic_add_f(float* p, float v){
  __hip_atomic_fetch_add(p, v, __ATOMIC_RELAXED, __HIP_MEMORY_SCOPE_AGENT);
}
__device__ inline void gload16(const void* g, void* l){
  __builtin_amdgcn_global_load_lds(
      (const __attribute__((address_space(1))) unsigned int*)g,
      (__attribute__((address_space(3))) unsigned int*)l, 16, 0, 0);
}
__device__ inline float silu(float x){ return x / (1.f + __expf(-x)); }

// decode pair-block b (0..54) -> (qb, pb), qb <= pb < 10
__device__ inline void decode_blk(int b, int& qb, int& pb){
  int q = 0, rem = b;
  while (rem >= 10 - q){ rem -= 10 - q; q++; }
  qb = q; pb = q + rem;
}

// full 4x4 pair block for one l (CNT components)
template<int CNT>
__device__ inline void ps_block(const float* __restrict__ cl, int qb, int pb, int off,
                                float nrm, bool diag, unsigned short* ob){
  float cq[4][CNT], cp[4][CNT];
  #pragma unroll
  for (int i = 0; i < 4; i++)
    #pragma unroll
    for (int k = 0; k < CNT; k++){
      cq[i][k] = cl[(qb*4 + i)*9 + off + k];
      cp[i][k] = cl[(pb*4 + i)*9 + off + k];
    }
  #pragma unroll
  for (int qi = 0; qi < 4; qi++)
    #pragma unroll
    for (int pi = 0; pi < 4; pi++){
      float v = 0.f;
      #pragma unroll
      for (int k = 0; k < CNT; k++) v += cq[qi][k] * cp[pi][k];
      v *= nrm;
      if (diag && qi > pi) v = 0.f;
      ob[qi*4 + pi] = f2bf(v);
    }
}

// half (2 qi rows x 4 pi): 8 outputs
template<int CNT>
__device__ inline void ps_block_half(const float* __restrict__ cl, int qb, int pb, int off,
                                     float nrm, bool diag, int qh, unsigned short* ob){
  float cq[2][CNT], cp[4][CNT];
  #pragma unroll
  for (int i = 0; i < 2; i++)
    #pragma unroll
    for (int k = 0; k < CNT; k++)
      cq[i][k] = cl[(qb*4 + qh*2 + i)*9 + off + k];
  #pragma unroll
  for (int i = 0; i < 4; i++)
    #pragma unroll
    for (int k = 0; k < CNT; k++)
      cp[i][k] = cl[(pb*4 + i)*9 + off + k];
  #pragma unroll
  for (int qi = 0; qi < 2; qi++)
    #pragma unroll
    for (int pi = 0; pi < 4; pi++){
      int qg = qh*2 + qi;
      float v = 0.f;
      #pragma unroll
      for (int k = 0; k < CNT; k++) v += cq[qi][k] * cp[pi][k];
      v *= nrm;
      if (diag && qg > pi) v = 0.f;
      ob[qi*4 + pi] = f2bf(v);
    }
}

// quarter (1 qi row x 4 pi): 4 outputs
template<int CNT>
__device__ inline void ps_block_quarter(const float* __restrict__ cl, int qb, int pb, int off,
                                        float nrm, bool diag, int qi, unsigned short* ob){
  float cq[CNT], cp[4][CNT];
  #pragma unroll
  for (int k = 0; k < CNT; k++) cq[k] = cl[(qb*4 + qi)*9 + off + k];
  #pragma unroll
  for (int i = 0; i < 4; i++)
    #pragma unroll
    for (int k = 0; k < CNT; k++)
      cp[i][k] = cl[(pb*4 + i)*9 + off + k];
  #pragma unroll
  for (int pi = 0; pi < 4; pi++){
    float v = 0.f;
    #pragma unroll
    for (int k = 0; k < CNT; k++) v += cq[k] * cp[pi][k];
    v *= nrm;
    if (diag && qi > pi) v = 0.f;
    ob[pi] = f2bf(v);
  }
}

__device__ inline int block_scan_excl(int v, int tid, int* lds){
  int lane = tid & 63, w = tid >> 6;
  int x = v;
  #pragma unroll
  for (int d = 1; d < 64; d <<= 1){
    int y = __shfl_up(x, d, 64);
    if (lane >= d) x += y;
  }
  if (lane == 63) lds[w] = x;
  __syncthreads();
  int wsum = 0;
  for (int i = 0; i < w; i++) wsum += lds[i];
  return wsum + x - v;
}

// ---------------- edge hist (2048 blocks) + atom hist (64 blocks), fused --------------
__global__ __launch_bounds__(256) void k_hist(const int* __restrict__ ei,
                                              const int* __restrict__ numbers,
                                              int* __restrict__ cnt64k,
                                              int* __restrict__ bhist){
  __shared__ int h[4];
  int blk = blockIdx.x, tid = threadIdx.x;
  if (blk < 2048){
    int e = blk * 256 + tid;
    int key = ei[NE + e] * 4 + numbers[ei[e]];
    atomicAdd(&cnt64k[key], 1);
  } else {
    if (tid < 4) h[tid] = 0;
    __syncthreads();
    atomicAdd(&h[numbers[(blk - 2048) * 256 + tid]], 1);
    __syncthreads();
    if (tid < 4) bhist[(blk - 2048) * 4 + tid] = h[tid];
  }
}

__global__ __launch_bounds__(256) void k_scanA(const int* __restrict__ cnt64k,
                                               int* __restrict__ bsum){
  __shared__ int lds[4];
  int tid = threadIdx.x;
  int v = cnt64k[blockIdx.x * 256 + tid];
  int lane = tid & 63;
  #pragma unroll
  for (int m = 32; m; m >>= 1) v += __shfl_xor(v, m, 64);
  if (lane == 0) lds[tid >> 6] = v;
  __syncthreads();
  if (tid == 0) bsum[blockIdx.x] = lds[0] + lds[1] + lds[2] + lds[3];
}

// scan of 256 block sums + atom-species offsets (fused serial tail)
__global__ __launch_bounds__(256) void k_scanB(const int* __restrict__ bsum,
                                               int* __restrict__ boff, int* __restrict__ starts,
                                               const int* __restrict__ bhist,
                                               int* __restrict__ boffs, int* __restrict__ ints){
  __shared__ int lds[4];
  int tid = threadIdx.x;
  int v = bsum[tid];
  int e = block_scan_excl(v, tid, lds);
  boff[tid] = e;
  if (tid == 0){
    starts[65536] = NE;
    int* cnt = ints; int* offs = ints + 8;
    int tot[4] = {0,0,0,0};
    for (int b = 0; b < 64; b++)
      for (int s = 0; s < 4; s++) tot[s] += bhist[b*4 + s];
    int o = 0;
    for (int s = 0; s < 4; s++){ cnt[s] = tot[s]; offs[s] = o; o += tot[s]; }
    offs[4] = o;
    int run[4];
    for (int s = 0; s < 4; s++) run[s] = offs[s];
    for (int b = 0; b < 64; b++)
      for (int s = 0; s < 4; s++){ boffs[b*4 + s] = run[s]; run[s] += bhist[b*4 + s]; }
  }
}

__global__ __launch_bounds__(256) void k_scanC(const int* __restrict__ cnt64k,
                                               const int* __restrict__ boff,
                                               int* __restrict__ starts, int* __restrict__ cursor){
  __shared__ int lds[4];
  int tid = threadIdx.x;
  int bin = blockIdx.x * 256 + tid;
  int v = cnt64k[bin];
  int e = block_scan_excl(v, tid, lds) + boff[blockIdx.x];
  starts[bin] = e;
  cursor[bin] = e;
}

__global__ __launch_bounds__(256) void k_sortperm(const int* __restrict__ ei,
                                                  const int* __restrict__ numbers,
                                                  int* __restrict__ cursor, int* __restrict__ perm){
  int e = blockIdx.x * 256 + threadIdx.x;
  if (e < NE){
    int key = ei[NE + e] * 4 + numbers[ei[e]];
    int p = atomicAdd(&cursor[key], 1);
    perm[p] = e;
  }
}

__global__ __launch_bounds__(256) void k_aplace(const int* __restrict__ numbers,
                                                const int* __restrict__ boffs,
                                                int* __restrict__ list){
  __shared__ int ws[4][4];
  int tid = threadIdx.x, w = tid >> 6, lane = tid & 63;
  int i = blockIdx.x * 256 + tid;
  int sp = numbers[i];
  int rank = 0;
  #pragma unroll
  for (int s = 0; s < 4; s++){
    unsigned long long m = __ballot(sp == s);
    if (s == sp) rank = __popcll(m & (((unsigned long long)1 << lane) - 1));
    if (lane == 0) ws[w][s] = __popcll(m);
  }
  __syncthreads();
  int pre = 0;
  for (int w2 = 0; w2 < w; w2++) pre += ws[w2][sp];
  list[boffs[blockIdx.x * 4 + sp] + pre + rank] = i;
}

// ---------------- fused per-atom (512 thr, 8 waves): geometry -> species-uniform
//                  accumulate -> U-mix -> 7-wave ps + Gram stats ----------------------
__global__ __launch_bounds__(512) void k_atom(
    const float* __restrict__ pos, const float* __restrict__ cells,
    const int* __restrict__ ei, const float* __restrict__ eoff,
    const int* __restrict__ batch, const int* __restrict__ startsK,
    const int* __restrict__ perm, const float* __restrict__ U,
    unsigned short* __restrict__ ps, float* __restrict__ stats)
{
  __shared__ float Rl[128][NMX];
  __shared__ float Yl[128][NSPH];
  __shared__ float csr[360];
  __shared__ float cl[360];
  __shared__ float ul[16];
  int atom = blockIdx.x;
  int tid = threadIdx.x;
  if (tid < 16) ul[tid] = U[tid];
  int e0 = startsK[atom * 4], e1 = startsK[atom * 4 + 4];
  float px = pos[atom*3+0], py = pos[atom*3+1], pz = pos[atom*3+2];
  int sp = tid >> 7, nk = tid & 127;       // species-uniform waves
  int n = nk / 9, k = nk - n * 9;          // valid when nk < 90
  int aS = startsK[atom * 4 + sp], aE = startsK[atom * 4 + sp + 1];
  float acc = 0.f;
  for (int base = e0; base < e1; base += 128){
    int nch = min(128, e1 - base);
    if (tid < nch){
      int e = perm[base + tid];
      int snd = ei[e];
      const float* C = cells + (size_t)batch[snd] * 9;
      float o0 = eoff[e*3+0], o1 = eoff[e*3+1], o2 = eoff[e*3+2];
      float rx = px - pos[snd*3+0] + o0*C[0] + o1*C[3] + o2*C[6];
      float ry = py - pos[snd*3+1] + o0*C[1] + o1*C[4] + o2*C[7];
      float rz = pz - pos[snd*3+2] + o0*C[2] + o1*C[5] + o2*C[8];
      float r = sqrtf(rx*rx + ry*ry + rz*rz + 1e-12f);
      float inv = 1.f / r;
      float hx = rx*inv, hy = ry*inv, hz = rz*inv;
      float fc = (r < 5.f) ? (0.5f * (__cosf(r * 0.6283185307179586f) + 1.f)) : 0.f;
      #pragma unroll
      for (int nn = 0; nn < NMX; nn++){
        float d = r - (5.f/9.f) * (float)nn;
        Rl[tid][nn] = __expf(-2.f * d * d) * fc;
      }
      Yl[tid][0] = 0.28209479177387814f;
      Yl[tid][1] = 0.4886025119029199f * hy;
      Yl[tid][2] = 0.4886025119029199f * hz;
      Yl[tid][3] = 0.4886025119029199f * hx;
      Yl[tid][4] = 1.0925484305920792f * hx * hy;
      Yl[tid][5] = 1.0925484305920792f * hy * hz;
      Yl[tid][6] = 0.31539156525252005f * (3.f * hz * hz - 1.f);
      Yl[tid][7] = 1.0925484305920792f * hx * hz;
      Yl[tid][8] = 0.5462742152960396f * (hx * hx - hy * hy);
    }
    __syncthreads();
    if (nk < 90){
      int lo2 = max(aS, base), hi2 = min(aE, base + nch);
      for (int e = lo2; e < hi2; e++){
        int j = e - base;
        acc += Rl[j][n] * Yl[j][k];
      }
    }
    __syncthreads();
  }
  if (nk < 90) csr[sp * 90 + nk] = acc;
  __syncthreads();
  if (tid < 360){
    int a = tid / 90, nq = tid % 90;
    cl[tid] = ul[a*4+0]*csr[nq] + ul[a*4+1]*csr[90+nq]
            + ul[a*4+2]*csr[180+nq] + ul[a*4+3]*csr[270+nq];
  }
  __syncthreads();
  // ps: w0..3 -> l=2 quarters (qi=w), w4/5 -> l=1 halves, w6 -> l=0 full, w7 -> pad+stats
  int w8 = tid >> 6, b = tid & 63;
  if (w8 < 4 && b < 55){
    int qb, pb;
    decode_blk(b, qb, pb);
    bool diag = (qb == pb);
    unsigned short ob[4];
    ps_block_quarter<5>(cl, qb, pb, 4, 0.4472135954999579f, diag, w8, ob);
    unsigned short* dst = ps + (size_t)atom * FR + b * 48 + 32 + w8 * 4;
    *reinterpret_cast<u16x4*>(dst) = *(const u16x4*)ob;
  } else if ((w8 == 4 || w8 == 5) && b < 55){
    int qh = w8 - 4;
    int qb, pb;
    decode_blk(b, qb, pb);
    bool diag = (qb == pb);
    unsigned short ob[8];
    ps_block_half<3>(cl, qb, pb, 1, 0.5773502691896258f, diag, qh, ob);
    unsigned short* dst = ps + (size_t)atom * FR + b * 48 + 16 + qh * 8;
    *reinterpret_cast<u16x8*>(dst) = *(const u16x8*)ob;
  } else if (w8 == 6 && b < 55){
    int qb, pb;
    decode_blk(b, qb, pb);
    bool diag = (qb == pb);
    unsigned short ob[16];
    ps_block<1>(cl, qb, pb, 0, 1.f, diag, ob);
    unsigned short* dst = ps + (size_t)atom * FR + b * 48;
    *reinterpret_cast<u16x8*>(dst)     = *(const u16x8*)&ob[0];
    *reinterpret_cast<u16x8*>(dst + 8) = *(const u16x8*)&ob[8];
  } else if (w8 == 7){
    if (b < 6){
      unsigned short zb[8] = {0,0,0,0,0,0,0,0};
      *reinterpret_cast<u16x8*>(ps + (size_t)atom * FR + 2640 + b * 8) = *(const u16x8*)zb;
    }
    // LN stats closed form (see R16)
    float c1 = 0.f, c2 = 0.f;
    if (b >= 8 && b < 17){
      int kk = b - 8;
      float S = 0.f;
      for (int q = 0; q < 40; q++) S += cl[q*9 + kk];
      float nrm = (kk == 0) ? 1.f : ((kk < 4) ? 0.5773502691896258f : 0.4472135954999579f);
      c1 = nrm * S * S;
    } else if (b >= 24 && b < 46){
      int j = b - 24;
      int ka = g_ka[j], kb = g_kb[j];
      float G = 0.f;
      for (int q = 0; q < 40; q++) G += cl[q*9 + ka] * cl[q*9 + kb];
      float n2 = (ka == 0) ? 1.f : ((ka < 4) ? (1.f/3.f) : 0.2f);
      float mul = (ka == kb) ? 1.f : 2.f;
      c2 = n2 * mul * G * G;
    }
    #pragma unroll
    for (int m = 32; m; m >>= 1){ c1 += __shfl_xor(c1, m, 64); c2 += __shfl_xor(c2, m, 64); }
    if (b == 0){
      float mean = c1 * (1.f / FF);
      float var = c2 * (1.f / FF) - mean * mean;
      var = fmaxf(var, 0.f);
      stats[2*atom]   = mean;
      stats[2*atom+1] = rsqrtf(var + 1e-5f);
    }
  }
}

// ---------------- weight prep v3: SINGLE pass over W1, all 4 species at once ----------
__global__ __launch_bounds__(256) void k_wg3(
    const float* __restrict__ W1, const float* __restrict__ U,
    const float* __restrict__ gamma, const float* __restrict__ beta,
    unsigned short* __restrict__ Wg, float* __restrict__ gW, float* __restrict__ bW)
{
  __shared__ unsigned short og[4][64][64]; // [s][fi][ni], 32 KB
  int n0 = blockIdx.x * 64, f0 = blockIdx.y * 64;
  int tid = threadIdx.x, ni = tid & 63;
  float u[4][4];
  #pragma unroll
  for (int a = 0; a < 4; a++)
    #pragma unroll
    for (int s = 0; s < 4; s++) u[a][s] = U[a*4 + s];
  float gs[4] = {0,0,0,0}, bs[4] = {0,0,0,0};
  for (int rep = 0; rep < 16; rep++){
    int fi = rep * 4 + (tid >> 6);
    int fp = f0 + fi;
    int b = fp / 48, r = fp % 48;
    int l = r >> 4, qi = (r >> 2) & 3, pi = r & 3;
    float tg[4] = {0,0,0,0}, tb[4] = {0,0,0,0};
    if (b < 55){
      int qb, pb;
      decode_blk(b, qb, pb);
      bool zero = (qb == pb) && (qi > pi);
      if (!zero){
        int q = qb*4 + qi, p = pb*4 + pi;
        int fa = (q * 40 + p) * 3 + l;
        float ga = gamma[fa], ba = beta[fa];
        float wm[4] = {0,0,0,0};
        #pragma unroll
        for (int a = 0; a < 4; a++){
          float wa = W1[(size_t)a * FF * 512 + (size_t)fa * 512 + n0 + ni];
          #pragma unroll
          for (int s = 0; s < 4; s++) wm[s] += u[a][s] * wa;
        }
        #pragma unroll
        for (int s = 0; s < 4; s++){ tg[s] = ga * wm[s]; tb[s] = ba * wm[s]; }
        if (p != q){
          int fb = (p * 40 + q) * 3 + l;
          float gb = gamma[fb], bb = beta[fb];
          float wn[4] = {0,0,0,0};
          #pragma unroll
          for (int a = 0; a < 4; a++){
            float wb = W1[(size_t)a * FF * 512 + (size_t)fb * 512 + n0 + ni];
            #pragma unroll
            for (int s = 0; s < 4; s++) wn[s] += u[a][s] * wb;
          }
          #pragma unroll
          for (int s = 0; s < 4; s++){ tg[s] += gb * wn[s]; tb[s] += bb * wn[s]; }
        }
      }
    }
    #pragma unroll
    for (int s = 0; s < 4; s++){
      og[s][fi][ni] = f2bf(tg[s]);
      gs[s] += tg[s];
      bs[s] += tb[s];
    }
  }
  #pragma unroll
  for (int s = 0; s < 4; s++){
    atomic_add_f(&gW[s * 512 + n0 + ni], gs[s]);
    atomic_add_f(&bW[s * 512 + n0 + ni], bs[s]);
  }
  __syncthreads();
  for (int it = 0; it < 8; it++){
    int idx = it * 256 + tid;      // 2048 u16x8 chunks: [s][nn][c]
    int c = idx & 7;
    int rrow = idx >> 3;
    int s = rrow >> 6, nn = rrow & 63;
    unsigned short o[8];
    #pragma unroll
    for (int j = 0; j < 8; j++) o[j] = og[s][c*8 + j][nn];
    *reinterpret_cast<u16x8*>(&Wg[((size_t)s * 512 + n0 + nn) * FR + f0 + c * 8]) = *(const u16x8*)o;
  }
}

__global__ __launch_bounds__(256) void k_w2t(
    const float* __restrict__ W2, const float* __restrict__ U,
    unsigned short* __restrict__ W2t)
{
  __shared__ float t[64][65];
  int n0 = blockIdx.x * 64, k0 = blockIdx.y * 64, s = blockIdx.z;
  float u0 = U[s], u1 = U[4+s], u2 = U[8+s], u3 = U[12+s];
  int tid = threadIdx.x;
  #pragma unroll 4
  for (int rep = 0; rep < 16; rep++){
    int idx = rep * 256 + tid;
    int ki = idx >> 6, ni = idx & 63;
    size_t base = (size_t)(k0 + ki) * 512 + (n0 + ni);
    t[ki][ni] = u0*W2[base] + u1*W2[base + 512*512]
              + u2*W2[base + 2*512*512] + u3*W2[base + 3*512*512];
  }
  __syncthreads();
  #pragma unroll 4
  for (int rep = 0; rep < 16; rep++){
    int idx = rep * 256 + tid;
    int ni = idx >> 6, ki = idx & 63;
    W2t[((size_t)s * 512 + n0 + ni) * 512 + k0 + ki] = f2bf(t[ki][ni]);
  }
}

__global__ void k_w3(const float* __restrict__ W3, const float* __restrict__ U,
                     float* __restrict__ W3s)
{
  int idx = blockIdx.x * 256 + threadIdx.x;
  if (idx < 4 * 512){
    int s = idx >> 9, k = idx & 511;
    W3s[idx] = U[s]*W3[k] + U[4+s]*W3[512+k] + U[8+s]*W3[2*512+k] + U[12+s]*W3[3*512+k];
  }
}

// ---------------- GEMM template (128x128 tile, BK=64, bf16 MFMA) ----------------
template<int EPI, int NSPLIT>
__global__ __launch_bounds__(256) void k_gemm(
    const unsigned short* __restrict__ Ag, int lda, int K,
    const unsigned short* __restrict__ Btg,
    const int* __restrict__ list, const int* __restrict__ offs, const int* __restrict__ cnt,
    unsigned short* __restrict__ pout,
    const float* __restrict__ W3s, float* __restrict__ pacc)
{
  __shared__ alignas(16) char smem[32768];
  const int NV = 4 * NSPLIT;
  int b = blockIdx.x;
  int y = (b & 7) + 8 * (b / (8 * NV));
  int v = (b >> 3) % NV;
  int x = v & 3, kh = v >> 2;

  int s = 0, t = y;
  for (; s < 4; s++){
    int nts = (cnt[s] + 127) >> 7;
    if (t < nts) break;
    t -= nts;
  }
  if (s >= 4) return;
  int cntS = cnt[s], offS = offs[s];
  int rt = t, n0 = x * 128;
  int tid = threadIdx.x, w = tid >> 6, lane = tid & 63;
  int wr = w >> 1, wc = w & 1;

  const unsigned short* Bts = Btg + (size_t)s * 512 * K;
  const unsigned short* gA[4];
  const unsigned short* gB[4];
  char* lA[4];
  char* lB[4];
  #pragma unroll
  for (int it = 0; it < 4; it++){
    int g = it * 4 + w;
    int idx = g * 64 + lane;
    int row = idx >> 3, ch = idx & 7;
    int cg = ch ^ (row & 7);
    int gr = rt * 128 + row; gr = gr < cntS ? gr : cntS - 1;
    int atom = list[offS + gr];
    gA[it] = Ag + (size_t)atom * lda + cg * 8;
    lA[it] = smem + g * 1024;
    gB[it] = Bts + (size_t)(n0 + row) * K + cg * 8;
    lB[it] = smem + 16384 + g * 1024;
  }

  int hi = lane >> 4, lo = lane & 15;
  f32x4 acc[4][4];
  #pragma unroll
  for (int mi = 0; mi < 4; mi++)
    #pragma unroll
    for (int ni = 0; ni < 4; ni++)
      #pragma unroll
      for (int r = 0; r < 4; r++) acc[mi][ni][r] = 0.f;

  int abase[4], a7[4], bbase[4], b7[4];
  #pragma unroll
  for (int mi = 0; mi < 4; mi++){ int row = wr*64 + mi*16 + lo; abase[mi] = row*128; a7[mi] = row & 7; }
  #pragma unroll
  for (int ni = 0; ni < 4; ni++){ int row = wc*64 + ni*16 + lo; bbase[ni] = 16384 + row*128; b7[ni] = row & 7; }

  int nk = K / 64;
  int k0 = ((nk * kh) / NSPLIT) * 64;
  int k1 = ((nk * (kh + 1)) / NSPLIT) * 64;

  for (int kt = k0; kt < k1; kt += 64){
    #pragma unroll
    for (int it = 0; it < 4; it++) gload16(gA[it] + kt, lA[it]);
    #pragma unroll
    for (int it = 0; it < 4; it++) gload16(gB[it] + kt, lB[it]);
    __syncthreads();
    #pragma unroll
    for (int kk = 0; kk < 2; kk++){
      bf16x8 af[4], bfr[4];
      #pragma unroll
      for (int mi = 0; mi < 4; mi++)
        af[mi] = *(const bf16x8*)(smem + abase[mi] + (((kk*4 + hi) ^ a7[mi]) << 4));
      #pragma unroll
      for (int ni = 0; ni < 4; ni++)
        bfr[ni] = *(const bf16x8*)(smem + bbase[ni] + (((kk*4 + hi) ^ b7[ni]) << 4));
      #pragma unroll
      for (int mi = 0; mi < 4; mi++)
        #pragma unroll
        for (int ni = 0; ni < 4; ni++)
          acc[mi][ni] = __builtin_amdgcn_mfma_f32_16x16x32_bf16(af[mi], bfr[ni], acc[mi][ni], 0, 0, 0);
    }
    __syncthreads();
  }

  int gn[4];
  #pragma unroll
  for (int ni = 0; ni < 4; ni++) gn[ni] = n0 + wc*64 + ni*16 + lo;

  if (EPI == 0){
    #pragma unroll
    for (int mi = 0; mi < 4; mi++){
      #pragma unroll
      for (int j = 0; j < 4; j++){
        int gr = rt*128 + wr*64 + mi*16 + hi*4 + j;
        if (gr < cntS){
          int atom = list[offS + gr];
          #pragma unroll
          for (int ni = 0; ni < 4; ni++)
            pout[((size_t)kh * NA + atom) * 512 + gn[ni]] = f2bf(acc[mi][ni][j]);
        }
      }
    }
  } else {
    float w3v[4];
    #pragma unroll
    for (int ni = 0; ni < 4; ni++) w3v[ni] = W3s[s * 512 + gn[ni]];
    float* pslot = pacc + (size_t)(x * 2 + wc) * NA;
    #pragma unroll
    for (int mi = 0; mi < 4; mi++){
      #pragma unroll
      for (int j = 0; j < 4; j++){
        int gr = rt*128 + wr*64 + mi*16 + hi*4 + j;
        if (gr < cntS){
          int atom = list[offS + gr];
          float pdot = 0.f;
          #pragma unroll
          for (int ni = 0; ni < 4; ni++)
            pdot += silu(acc[mi][ni][j]) * w3v[ni];
          pdot += __shfl_xor(pdot, 1, 16);
          pdot += __shfl_xor(pdot, 2, 16);
          pdot += __shfl_xor(pdot, 4, 16);
          pdot += __shfl_xor(pdot, 8, 16);
          if (lo == 0) pslot[atom] = pdot;
        }
      }
    }
  }
}

// ---------------- epilogue: combine 4 split-K partials + LN-affine + silu -> h1 -------
__global__ __launch_bounds__(256) void k_epi(
    const unsigned short* __restrict__ pbuf, const float* __restrict__ stats,
    const float* __restrict__ gW, const float* __restrict__ bW,
    const int* __restrict__ numbers, unsigned short* __restrict__ h1)
{
  int w = threadIdx.x >> 6, lane = threadIdx.x & 63;
  int atom = blockIdx.x * 4 + w;
  int s = numbers[atom];
  float mean = stats[2*atom], rstd = stats[2*atom+1];
  int c0 = lane * 8;
  u16x8 a0 = *reinterpret_cast<const u16x8*>(pbuf + (size_t)atom * 512 + c0);
  u16x8 a1 = *reinterpret_cast<const u16x8*>(pbuf + (size_t)(NA + atom) * 512 + c0);
  u16x8 a2 = *reinterpret_cast<const u16x8*>(pbuf + (size_t)(2*NA + atom) * 512 + c0);
  u16x8 a3 = *reinterpret_cast<const u16x8*>(pbuf + (size_t)(3*NA + atom) * 512 + c0);
  unsigned short o[8];
  #pragma unroll
  for (int j = 0; j < 8; j++){
    int c = c0 + j;
    float acc = (bf2f(a0[j]) + bf2f(a1[j])) + (bf2f(a2[j]) + bf2f(a3[j]));
    float vv = rstd * acc + bW[s*512 + c] - mean * rstd * gW[s*512 + c];
    o[j] = f2bf(silu(vv));
  }
  *reinterpret_cast<u16x8*>(h1 + (size_t)atom * 512 + c0) = *(const u16x8*)o;
}

// ---------------- final: sum 8 pacc partials/atom, wave-uniform molecule atomic -------
__global__ __launch_bounds__(256) void k_final2(
    const float* __restrict__ pacc, const int* __restrict__ numbers,
    const int* __restrict__ batch, const float* __restrict__ Wc,
    float* __restrict__ molOut)
{
  int atom = blockIdx.x * 256 + threadIdx.x;
  int lane = threadIdx.x & 63;
  float sum = 0.f;
  #pragma unroll
  for (int p = 0; p < 8; p++) sum += pacc[(size_t)p * NA + atom];
  float val = sum * (1.f / 128.f) + Wc[numbers[atom]];
  int mol = batch[atom];
  int m0 = __shfl(mol, 0, 64);
  int m63 = __shfl(mol, 63, 64);
  if (m0 == m63){
    #pragma unroll
    for (int m = 32; m; m >>= 1) val += __shfl_xor(val, m, 64);
    if (lane == 0) atomic_add_f(&molOut[mol], val);
  } else {
    atomic_add_f(&molOut[mol], val);
  }
}

extern "C" void kernel_launch(void* const* d_in, const int* in_sizes, int n_in,
                              void* d_out, int out_size, void* d_ws, size_t ws_size,
                              hipStream_t stream)
{
  const float* pos     = (const float*)d_in[0];
  const float* cells   = (const float*)d_in[1];
  const int*   numbers = (const int*)d_in[2];
  const int*   ei      = (const int*)d_in[3];
  const float* eoff    = (const float*)d_in[4];
  const int*   batch   = (const int*)d_in[5];
  const float* U       = (const float*)d_in[6];
  const float* gamma   = (const float*)d_in[7];
  const float* beta    = (const float*)d_in[8];
  const float* W1      = (const float*)d_in[9];
  const float* W2      = (const float*)d_in[10];
  const float* W3      = (const float*)d_in[11];
  const float* Wc      = (const float*)d_in[12];
  float* out = (float*)d_out;

  char* ws = (char*)d_ws;
  size_t off = 0;
  auto alloc = [&](size_t bytes) -> void* {
    void* p = ws + off;
    off += (bytes + 255) & ~(size_t)255;
    return p;
  };
  unsigned short* ps   = (unsigned short*)alloc((size_t)NA * FR * 2);      // 88 MB
  unsigned short* pbuf = (unsigned short*)alloc((size_t)4 * NA * 512 * 2); // 64 MB
  float* stats         = (float*)alloc((size_t)NA * 2 * 4);
  unsigned short* Wg1  = (unsigned short*)alloc((size_t)4 * 512 * FR * 2); // 11 MB
  unsigned short* W2t  = (unsigned short*)alloc((size_t)4 * 512 * 512 * 2);
  float* W3s           = (float*)alloc(4 * 512 * 4);
  unsigned short* h1   = (unsigned short*)alloc((size_t)NA * 512 * 2);
  float* pacc          = (float*)alloc((size_t)8 * NA * 4);
  int* list            = (int*)alloc(NA * 4);
  int* perm            = (int*)alloc((size_t)NE * 4);
  int* startsK         = (int*)alloc((65536 + 1) * 4);
  // contiguous zero-init region: cnt64k + gW + bW (one memset)
  int* cnt64k          = (int*)alloc(65536 * 4);
  float* gW            = (float*)alloc(4 * 512 * 4);
  float* bW            = (float*)alloc(4 * 512 * 4);
  int* cursor64k       = (int*)alloc(65536 * 4);
  int* bsum            = (int*)alloc(256 * 4);
  int* boff            = (int*)alloc(256 * 4);
  int* bhist           = (int*)alloc(64 * 4 * 4);
  int* boffs           = (int*)alloc(64 * 4 * 4);
  int* ints            = (int*)alloc(64);
  int* cnt = ints; int* offs = ints + 8;

  hipMemsetAsync(cnt64k, 0, 65536 * 4 + 2 * 4 * 512 * 4, stream);
  hipMemsetAsync(out, 0, (size_t)out_size * 4, stream);

  // edge hist (by recv*4+species) + atom hist, fused
  k_hist<<<2048 + 64, 256, 0, stream>>>(ei, numbers, cnt64k, bhist);
  k_scanA<<<256, 256, 0, stream>>>(cnt64k, bsum);
  k_scanB<<<1, 256, 0, stream>>>(bsum, boff, startsK, bhist, boffs, ints);
  k_scanC<<<256, 256, 0, stream>>>(cnt64k, boff, startsK, cursor64k);
  k_sortperm<<<NE / 256, 256, 0, stream>>>(ei, numbers, cursor64k, perm);
  k_aplace<<<NA / 256, 256, 0, stream>>>(numbers, boffs, list);

  // fused per-atom pipeline (512 threads, species-uniform waves, 7-wave ps split)
  k_atom<<<NA, 512, 0, stream>>>(pos, cells, ei, eoff, batch, startsK, perm, U, ps, stats);

  // weight prep (single pass over W1; W2 mix; W3 mix)
  k_wg3<<<dim3(8, 42), 256, 0, stream>>>(W1, U, gamma, beta, Wg1, gW, bW);
  k_w2t<<<dim3(8, 8, 4), 256, 0, stream>>>(W2, U, W2t);
  k_w3<<<8, 256, 0, stream>>>(W3, U, W3s);

  // GEMM1 split-K=4 (K=2688, 2176 blocks), then LN+silu epilogue
  k_gemm<0, 4><<<2176, 256, 0, stream>>>(ps, FR, FR, Wg1, list, offs, cnt,
                                         pbuf, nullptr, nullptr);
  k_epi<<<NA / 4, 256, 0, stream>>>(pbuf, stats, gW, bW, numbers, h1);

  // GEMM2 with fused silu + W3 dot -> per-atom partials (atomic-free)
  k_gemm<2, 1><<<544, 256, 0, stream>>>(h1, 512, 512, W2t, list, offs, cnt,
                                        nullptr, W3s, pacc);
  k_final2<<<NA / 256, 256, 0, stream>>>(pacc, numbers, batch, Wc, out);
}

// Round 18
// 311.198 us; speedup vs baseline: 1.0434x; 1.0434x over previous
//
#include <hip/hip_runtime.h>

#define NA   16384
#define NE   524288
#define NM   256
#define FF   4800
#define FR   2688   // folded K: 55 pair-blocks * 48 + 48 pad ; f' = b*48 + l*16 + qi*4 + pi
#define HH   512
#define NMX  10
#define NSPH 9

typedef __bf16 bf16x8 __attribute__((ext_vector_type(8)));
typedef float  f32x4  __attribute__((ext_vector_type(4)));
typedef unsigned short u16x8 __attribute__((ext_vector_type(8)));

__constant__ int g_ka[22] = {0, 1,1,1,2,2,3, 4,4,4,4,4, 5,5,5,5, 6,6,6, 7,7, 8};
__constant__ int g_kb[22] = {0, 1,2,3,2,3,3, 4,5,6,7,8, 5,6,7,8, 6,7,8, 7,8, 8};

__device__ inline unsigned short f2bf(float x){
  return __builtin_bit_cast(unsigned short, (__bf16)x);
}
__device__ inline float bf2f(unsigned short h){
  unsigned int u = ((unsigned int)h) << 16;
  return __builtin_bit_cast(float, u);
}
__device__ inline void atomic_add_f(float* p, float v){
  __hip_atomic_fetch_add(p, v, __ATOMIC_RELAXED, __HIP_MEMORY_SCOPE_AGENT);
}
__device__ inline void gload16(const void* g, void* l){
  __builtin_amdgcn_global_load_lds(
      (const __attribute__((address_space(1))) unsigned int*)g,
      (__attribute__((address_space(3))) unsigned int*)l, 16, 0, 0);
}
__device__ inline float silu(float x){ return x / (1.f + __expf(-x)); }

// decode pair-block b (0..54) -> (qb, pb), qb <= pb < 10
__device__ inline void decode_blk(int b, int& qb, int& pb){
  int q = 0, rem = b;
  while (rem >= 10 - q){ rem -= 10 - q; q++; }
  qb = q; pb = q + rem;
}

// full 4x4 pair block for one l (CNT components), outputs only
template<int CNT>
__device__ inline void ps_block(const float* __restrict__ cl, int qb, int pb, int off,
                                float nrm, bool diag, unsigned short* ob){
  float cq[4][CNT], cp[4][CNT];
  #pragma unroll
  for (int i = 0; i < 4; i++)
    #pragma unroll
    for (int k = 0; k < CNT; k++){
      cq[i][k] = cl[(qb*4 + i)*9 + off + k];
      cp[i][k] = cl[(pb*4 + i)*9 + off + k];
    }
  #pragma unroll
  for (int qi = 0; qi < 4; qi++)
    #pragma unroll
    for (int pi = 0; pi < 4; pi++){
      float v = 0.f;
      #pragma unroll
      for (int k = 0; k < CNT; k++) v += cq[qi][k] * cp[pi][k];
      v *= nrm;
      if (diag && qi > pi) v = 0.f;
      ob[qi*4 + pi] = f2bf(v);
    }
}

// half (2 qi rows x 4 pi) of a 4x4 pair block: 8 outputs, outputs only
template<int CNT>
__device__ inline void ps_block_half(const float* __restrict__ cl, int qb, int pb, int off,
                                     float nrm, bool diag, int qh, unsigned short* ob){
  float cq[2][CNT], cp[4][CNT];
  #pragma unroll
  for (int i = 0; i < 2; i++)
    #pragma unroll
    for (int k = 0; k < CNT; k++)
      cq[i][k] = cl[(qb*4 + qh*2 + i)*9 + off + k];
  #pragma unroll
  for (int i = 0; i < 4; i++)
    #pragma unroll
    for (int k = 0; k < CNT; k++)
      cp[i][k] = cl[(pb*4 + i)*9 + off + k];
  #pragma unroll
  for (int qi = 0; qi < 2; qi++)
    #pragma unroll
    for (int pi = 0; pi < 4; pi++){
      int qg = qh*2 + qi;
      float v = 0.f;
      #pragma unroll
      for (int k = 0; k < CNT; k++) v += cq[qi][k] * cp[pi][k];
      v *= nrm;
      if (diag && qg > pi) v = 0.f;
      ob[qi*4 + pi] = f2bf(v);
    }
}

__device__ inline int block_scan_excl(int v, int tid, int* lds){
  int lane = tid & 63, w = tid >> 6;
  int x = v;
  #pragma unroll
  for (int d = 1; d < 64; d <<= 1){
    int y = __shfl_up(x, d, 64);
    if (lane >= d) x += y;
  }
  if (lane == 63) lds[w] = x;
  __syncthreads();
  int wsum = 0;
  for (int i = 0; i < w; i++) wsum += lds[i];
  return wsum + x - v;
}

// ---------------- edge hist (2048 blocks) + atom hist (64 blocks), fused --------------
__global__ __launch_bounds__(256) void k_hist(const int* __restrict__ ei,
                                              const int* __restrict__ numbers,
                                              int* __restrict__ cnt64k,
                                              int* __restrict__ bhist){
  __shared__ int h[4];
  int blk = blockIdx.x, tid = threadIdx.x;
  if (blk < 2048){
    int e = blk * 256 + tid;
    int key = ei[NE + e] * 4 + numbers[ei[e]];
    atomicAdd(&cnt64k[key], 1);
  } else {
    if (tid < 4) h[tid] = 0;
    __syncthreads();
    atomicAdd(&h[numbers[(blk - 2048) * 256 + tid]], 1);
    __syncthreads();
    if (tid < 4) bhist[(blk - 2048) * 4 + tid] = h[tid];
  }
}

__global__ __launch_bounds__(256) void k_scanA(const int* __restrict__ cnt64k,
                                               int* __restrict__ bsum){
  __shared__ int lds[4];
  int tid = threadIdx.x;
  int v = cnt64k[blockIdx.x * 256 + tid];
  int lane = tid & 63;
  #pragma unroll
  for (int m = 32; m; m >>= 1) v += __shfl_xor(v, m, 64);
  if (lane == 0) lds[tid >> 6] = v;
  __syncthreads();
  if (tid == 0) bsum[blockIdx.x] = lds[0] + lds[1] + lds[2] + lds[3];
}

// scan of 256 block sums + atom-species offsets (fused serial tail)
__global__ __launch_bounds__(256) void k_scanB(const int* __restrict__ bsum,
                                               int* __restrict__ boff, int* __restrict__ starts,
                                               const int* __restrict__ bhist,
                                               int* __restrict__ boffs, int* __restrict__ ints){
  __shared__ int lds[4];
  int tid = threadIdx.x;
  int v = bsum[tid];
  int e = block_scan_excl(v, tid, lds);
  boff[tid] = e;
  if (tid == 0){
    starts[65536] = NE;
    int* cnt = ints; int* offs = ints + 8;
    int tot[4] = {0,0,0,0};
    for (int b = 0; b < 64; b++)
      for (int s = 0; s < 4; s++) tot[s] += bhist[b*4 + s];
    int o = 0;
    for (int s = 0; s < 4; s++){ cnt[s] = tot[s]; offs[s] = o; o += tot[s]; }
    offs[4] = o;
    int run[4];
    for (int s = 0; s < 4; s++) run[s] = offs[s];
    for (int b = 0; b < 64; b++)
      for (int s = 0; s < 4; s++){ boffs[b*4 + s] = run[s]; run[s] += bhist[b*4 + s]; }
  }
}

__global__ __launch_bounds__(256) void k_scanC(const int* __restrict__ cnt64k,
                                               const int* __restrict__ boff,
                                               int* __restrict__ starts, int* __restrict__ cursor){
  __shared__ int lds[4];
  int tid = threadIdx.x;
  int bin = blockIdx.x * 256 + tid;
  int v = cnt64k[bin];
  int e = block_scan_excl(v, tid, lds) + boff[blockIdx.x];
  starts[bin] = e;
  cursor[bin] = e;
}

__global__ __launch_bounds__(256) void k_sortperm(const int* __restrict__ ei,
                                                  const int* __restrict__ numbers,
                                                  int* __restrict__ cursor, int* __restrict__ perm){
  int e = blockIdx.x * 256 + threadIdx.x;
  if (e < NE){
    int key = ei[NE + e] * 4 + numbers[ei[e]];
    int p = atomicAdd(&cursor[key], 1);
    perm[p] = e;
  }
}

__global__ __launch_bounds__(256) void k_aplace(const int* __restrict__ numbers,
                                                const int* __restrict__ boffs,
                                                int* __restrict__ list){
  __shared__ int ws[4][4];
  int tid = threadIdx.x, w = tid >> 6, lane = tid & 63;
  int i = blockIdx.x * 256 + tid;
  int sp = numbers[i];
  int rank = 0;
  #pragma unroll
  for (int s = 0; s < 4; s++){
    unsigned long long m = __ballot(sp == s);
    if (s == sp) rank = __popcll(m & (((unsigned long long)1 << lane) - 1));
    if (lane == 0) ws[w][s] = __popcll(m);
  }
  __syncthreads();
  int pre = 0;
  for (int w2 = 0; w2 < w; w2++) pre += ws[w2][sp];
  list[boffs[blockIdx.x * 4 + sp] + pre + rank] = i;
}

// ---------------- fused per-atom: edge accum -> U-mix -> ps (6-wave) + Gram stats -----
__global__ __launch_bounds__(384) void k_atom(
    const float* __restrict__ pos, const float* __restrict__ cells,
    const int* __restrict__ ei, const float* __restrict__ eoff,
    const int* __restrict__ batch, const int* __restrict__ startsK,
    const int* __restrict__ perm, const float* __restrict__ U,
    unsigned short* __restrict__ ps, float* __restrict__ stats)
{
  __shared__ float Rl[64][NMX];
  __shared__ float Yl[64][NSPH];
  __shared__ float csr[360];
  __shared__ float cl[360];
  __shared__ float ul[16];
  int atom = blockIdx.x;
  int tid = threadIdx.x;
  if (tid < 16) ul[tid] = U[tid];
  int e0 = startsK[atom * 4], e1 = startsK[atom * 4 + 4];
  float px = pos[atom*3+0], py = pos[atom*3+1], pz = pos[atom*3+2];
  int sp = tid / 90, n = (tid % 90) / 9, k = tid % 9;
  int aS = 0, aE = 0;
  if (tid < 360){ aS = startsK[atom * 4 + sp]; aE = startsK[atom * 4 + sp + 1]; }
  float acc = 0.f;
  for (int base = e0; base < e1; base += 64){
    int nch = min(64, e1 - base);
    if (tid < nch){
      int e = perm[base + tid];
      int snd = ei[e];
      const float* C = cells + (size_t)batch[snd] * 9;
      float o0 = eoff[e*3+0], o1 = eoff[e*3+1], o2 = eoff[e*3+2];
      float rx = px - pos[snd*3+0] + o0*C[0] + o1*C[3] + o2*C[6];
      float ry = py - pos[snd*3+1] + o0*C[1] + o1*C[4] + o2*C[7];
      float rz = pz - pos[snd*3+2] + o0*C[2] + o1*C[5] + o2*C[8];
      float r = sqrtf(rx*rx + ry*ry + rz*rz + 1e-12f);
      float inv = 1.f / r;
      float hx = rx*inv, hy = ry*inv, hz = rz*inv;
      float fc = (r < 5.f) ? (0.5f * (__cosf(r * 0.6283185307179586f) + 1.f)) : 0.f;
      #pragma unroll
      for (int nn = 0; nn < NMX; nn++){
        float d = r - (5.f/9.f) * (float)nn;
        Rl[tid][nn] = __expf(-2.f * d * d) * fc;
      }
      Yl[tid][0] = 0.28209479177387814f;
      Yl[tid][1] = 0.4886025119029199f * hy;
      Yl[tid][2] = 0.4886025119029199f * hz;
      Yl[tid][3] = 0.4886025119029199f * hx;
      Yl[tid][4] = 1.0925484305920792f * hx * hy;
      Yl[tid][5] = 1.0925484305920792f * hy * hz;
      Yl[tid][6] = 0.31539156525252005f * (3.f * hz * hz - 1.f);
      Yl[tid][7] = 1.0925484305920792f * hx * hz;
      Yl[tid][8] = 0.5462742152960396f * (hx * hx - hy * hy);
    }
    __syncthreads();
    if (tid < 360){
      int lo2 = max(aS, base), hi2 = min(aE, base + nch);
      for (int e = lo2; e < hi2; e++){
        int j = e - base;
        acc += Rl[j][n] * Yl[j][k];
      }
    }
    __syncthreads();
  }
  if (tid < 360) csr[tid] = acc;
  __syncthreads();
  if (tid < 360){
    int a = tid / 90, nk = tid % 90;
    cl[tid] = ul[a*4+0]*csr[nk] + ul[a*4+1]*csr[90+nk]
            + ul[a*4+2]*csr[180+nk] + ul[a*4+3]*csr[270+nk];
  }
  __syncthreads();
  // ps: w0/w1 -> l=2 halves, w2/w3 -> l=1 halves, w4 -> l=0 full, w5 -> pad + Gram stats
  int w6 = tid >> 6, b = tid & 63;
  if (w6 <= 3 && b < 55){
    int l = (w6 < 2) ? 2 : 1;
    int qh = w6 & 1;
    int qb, pb;
    decode_blk(b, qb, pb);
    bool diag = (qb == pb);
    unsigned short ob[8];
    if (l == 2) ps_block_half<5>(cl, qb, pb, 4, 0.4472135954999579f, diag, qh, ob);
    else        ps_block_half<3>(cl, qb, pb, 1, 0.5773502691896258f, diag, qh, ob);
    unsigned short* dst = ps + (size_t)atom * FR + b * 48 + l * 16 + qh * 8;
    *reinterpret_cast<u16x8*>(dst) = *(const u16x8*)ob;
  } else if (w6 == 4 && b < 55){
    int qb, pb;
    decode_blk(b, qb, pb);
    bool diag = (qb == pb);
    unsigned short ob[16];
    ps_block<1>(cl, qb, pb, 0, 1.f, diag, ob);
    unsigned short* dst = ps + (size_t)atom * FR + b * 48;
    *reinterpret_cast<u16x8*>(dst)     = *(const u16x8*)&ob[0];
    *reinterpret_cast<u16x8*>(dst + 8) = *(const u16x8*)&ob[8];
  } else if (w6 == 5){
    if (b < 6){
      unsigned short zb[8] = {0,0,0,0,0,0,0,0};
      *reinterpret_cast<u16x8*>(ps + (size_t)atom * FR + 2640 + b * 8) = *(const u16x8*)zb;
    }
    // LN stats via closed form:
    //   s1 = sum_l nrm_l * sum_{k in l} S[k]^2,  S[k] = sum_q cl[q][k]
    //   s2 = sum_l nrm_l^2 * sum_{k,k' in l} G[k,k']^2,  G = sum_q cl[q][k]*cl[q][k']
    float c1 = 0.f, c2 = 0.f;
    if (b >= 8 && b < 17){
      int kk = b - 8;
      float S = 0.f;
      for (int q = 0; q < 40; q++) S += cl[q*9 + kk];
      float nrm = (kk == 0) ? 1.f : ((kk < 4) ? 0.5773502691896258f : 0.4472135954999579f);
      c1 = nrm * S * S;
    } else if (b >= 24 && b < 46){
      int j = b - 24;
      int ka = g_ka[j], kb = g_kb[j];
      float G = 0.f;
      for (int q = 0; q < 40; q++) G += cl[q*9 + ka] * cl[q*9 + kb];
      float n2 = (ka == 0) ? 1.f : ((ka < 4) ? (1.f/3.f) : 0.2f);
      float mul = (ka == kb) ? 1.f : 2.f;
      c2 = n2 * mul * G * G;
    }
    #pragma unroll
    for (int m = 32; m; m >>= 1){ c1 += __shfl_xor(c1, m, 64); c2 += __shfl_xor(c2, m, 64); }
    if (b == 0){
      float mean = c1 * (1.f / FF);
      float var = c2 * (1.f / FF) - mean * mean;
      var = fmaxf(var, 0.f);
      stats[2*atom]   = mean;
      stats[2*atom+1] = rsqrtf(var + 1e-5f);
    }
  }
}

// ---------------- weight prep v3: SINGLE pass over W1, all 4 species at once ----------
__global__ __launch_bounds__(256) void k_wg3(
    const float* __restrict__ W1, const float* __restrict__ U,
    const float* __restrict__ gamma, const float* __restrict__ beta,
    unsigned short* __restrict__ Wg, float* __restrict__ gW, float* __restrict__ bW)
{
  __shared__ unsigned short og[4][64][64]; // [s][fi][ni], 32 KB
  int n0 = blockIdx.x * 64, f0 = blockIdx.y * 64;
  int tid = threadIdx.x, ni = tid & 63;
  float u[4][4];
  #pragma unroll
  for (int a = 0; a < 4; a++)
    #pragma unroll
    for (int s = 0; s < 4; s++) u[a][s] = U[a*4 + s];
  float gs[4] = {0,0,0,0}, bs[4] = {0,0,0,0};
  for (int rep = 0; rep < 16; rep++){
    int fi = rep * 4 + (tid >> 6);
    int fp = f0 + fi;
    int b = fp / 48, r = fp % 48;
    int l = r >> 4, qi = (r >> 2) & 3, pi = r & 3;
    float tg[4] = {0,0,0,0}, tb[4] = {0,0,0,0};
    if (b < 55){
      int qb, pb;
      decode_blk(b, qb, pb);
      bool zero = (qb == pb) && (qi > pi);
      if (!zero){
        int q = qb*4 + qi, p = pb*4 + pi;
        int fa = (q * 40 + p) * 3 + l;
        float ga = gamma[fa], ba = beta[fa];
        float wm[4] = {0,0,0,0};
        #pragma unroll
        for (int a = 0; a < 4; a++){
          float wa = W1[(size_t)a * FF * 512 + (size_t)fa * 512 + n0 + ni];
          #pragma unroll
          for (int s = 0; s < 4; s++) wm[s] += u[a][s] * wa;
        }
        #pragma unroll
        for (int s = 0; s < 4; s++){ tg[s] = ga * wm[s]; tb[s] = ba * wm[s]; }
        if (p != q){
          int fb = (p * 40 + q) * 3 + l;
          float gb = gamma[fb], bb = beta[fb];
          float wn[4] = {0,0,0,0};
          #pragma unroll
          for (int a = 0; a < 4; a++){
            float wb = W1[(size_t)a * FF * 512 + (size_t)fb * 512 + n0 + ni];
            #pragma unroll
            for (int s = 0; s < 4; s++) wn[s] += u[a][s] * wb;
          }
          #pragma unroll
          for (int s = 0; s < 4; s++){ tg[s] += gb * wn[s]; tb[s] += bb * wn[s]; }
        }
      }
    }
    #pragma unroll
    for (int s = 0; s < 4; s++){
      og[s][fi][ni] = f2bf(tg[s]);
      gs[s] += tg[s];
      bs[s] += tb[s];
    }
  }
  #pragma unroll
  for (int s = 0; s < 4; s++){
    atomic_add_f(&gW[s * 512 + n0 + ni], gs[s]);
    atomic_add_f(&bW[s * 512 + n0 + ni], bs[s]);
  }
  __syncthreads();
  for (int it = 0; it < 8; it++){
    int idx = it * 256 + tid;      // 2048 u16x8 chunks: [s][nn][c]
    int c = idx & 7;
    int rrow = idx >> 3;
    int s = rrow >> 6, nn = rrow & 63;
    unsigned short o[8];
    #pragma unroll
    for (int j = 0; j < 8; j++) o[j] = og[s][c*8 + j][nn];
    *reinterpret_cast<u16x8*>(&Wg[((size_t)s * 512 + n0 + nn) * FR + f0 + c * 8]) = *(const u16x8*)o;
  }
}

// W2 mix (+ W3s slice computed by the x==0,y==0 block of each species)
__global__ __launch_bounds__(256) void k_w2t(
    const float* __restrict__ W2, const float* __restrict__ U,
    unsigned short* __restrict__ W2t,
    const float* __restrict__ W3, float* __restrict__ W3s)
{
  __shared__ float t[64][65];
  int n0 = blockIdx.x * 64, k0 = blockIdx.y * 64, s = blockIdx.z;
  float u0 = U[s], u1 = U[4+s], u2 = U[8+s], u3 = U[12+s];
  int tid = threadIdx.x;
  if (blockIdx.x == 0 && blockIdx.y == 0){
    for (int k = tid; k < 512; k += 256)
      W3s[s*512 + k] = u0*W3[k] + u1*W3[512+k] + u2*W3[2*512+k] + u3*W3[3*512+k];
  }
  #pragma unroll 4
  for (int rep = 0; rep < 16; rep++){
    int idx = rep * 256 + tid;
    int ki = idx >> 6, ni = idx & 63;
    size_t base = (size_t)(k0 + ki) * 512 + (n0 + ni);
    t[ki][ni] = u0*W2[base] + u1*W2[base + 512*512]
              + u2*W2[base + 2*512*512] + u3*W2[base + 3*512*512];
  }
  __syncthreads();
  #pragma unroll 4
  for (int rep = 0; rep < 16; rep++){
    int idx = rep * 256 + tid;
    int ni = idx >> 6, ki = idx & 63;
    W2t[((size_t)s * 512 + n0 + ni) * 512 + k0 + ki] = f2bf(t[ki][ni]);
  }
}

// ---------------- GEMM template (128x128 tile, BK=64, bf16 MFMA) ----------------
template<int EPI, int NSPLIT>
__global__ __launch_bounds__(256) void k_gemm(
    const unsigned short* __restrict__ Ag, int lda, int K,
    const unsigned short* __restrict__ Btg,
    const int* __restrict__ list, const int* __restrict__ offs, const int* __restrict__ cnt,
    unsigned short* __restrict__ pout,
    const float* __restrict__ W3s, float* __restrict__ pacc)
{
  __shared__ alignas(16) char smem[32768];
  const int NV = 4 * NSPLIT;
  int b = blockIdx.x;
  int y = (b & 7) + 8 * (b / (8 * NV));
  int v = (b >> 3) % NV;
  int x = v & 3, kh = v >> 2;

  int s = 0, t = y;
  for (; s < 4; s++){
    int nts = (cnt[s] + 127) >> 7;
    if (t < nts) break;
    t -= nts;
  }
  if (s >= 4) return;
  int cntS = cnt[s], offS = offs[s];
  int rt = t, n0 = x * 128;
  int tid = threadIdx.x, w = tid >> 6, lane = tid & 63;
  int wr = w >> 1, wc = w & 1;

  const unsigned short* Bts = Btg + (size_t)s * 512 * K;
  const unsigned short* gA[4];
  const unsigned short* gB[4];
  char* lA[4];
  char* lB[4];
  #pragma unroll
  for (int it = 0; it < 4; it++){
    int g = it * 4 + w;
    int idx = g * 64 + lane;
    int row = idx >> 3, ch = idx & 7;
    int cg = ch ^ (row & 7);
    int gr = rt * 128 + row; gr = gr < cntS ? gr : cntS - 1;
    int atom = list[offS + gr];
    gA[it] = Ag + (size_t)atom * lda + cg * 8;
    lA[it] = smem + g * 1024;
    gB[it] = Bts + (size_t)(n0 + row) * K + cg * 8;
    lB[it] = smem + 16384 + g * 1024;
  }

  int hi = lane >> 4, lo = lane & 15;
  f32x4 acc[4][4];
  #pragma unroll
  for (int mi = 0; mi < 4; mi++)
    #pragma unroll
    for (int ni = 0; ni < 4; ni++)
      #pragma unroll
      for (int r = 0; r < 4; r++) acc[mi][ni][r] = 0.f;

  int abase[4], a7[4], bbase[4], b7[4];
  #pragma unroll
  for (int mi = 0; mi < 4; mi++){ int row = wr*64 + mi*16 + lo; abase[mi] = row*128; a7[mi] = row & 7; }
  #pragma unroll
  for (int ni = 0; ni < 4; ni++){ int row = wc*64 + ni*16 + lo; bbase[ni] = 16384 + row*128; b7[ni] = row & 7; }

  int nk = K / 64;
  int k0 = ((nk * kh) / NSPLIT) * 64;
  int k1 = ((nk * (kh + 1)) / NSPLIT) * 64;

  for (int kt = k0; kt < k1; kt += 64){
    #pragma unroll
    for (int it = 0; it < 4; it++) gload16(gA[it] + kt, lA[it]);
    #pragma unroll
    for (int it = 0; it < 4; it++) gload16(gB[it] + kt, lB[it]);
    __syncthreads();
    #pragma unroll
    for (int kk = 0; kk < 2; kk++){
      bf16x8 af[4], bfr[4];
      #pragma unroll
      for (int mi = 0; mi < 4; mi++)
        af[mi] = *(const bf16x8*)(smem + abase[mi] + (((kk*4 + hi) ^ a7[mi]) << 4));
      #pragma unroll
      for (int ni = 0; ni < 4; ni++)
        bfr[ni] = *(const bf16x8*)(smem + bbase[ni] + (((kk*4 + hi) ^ b7[ni]) << 4));
      #pragma unroll
      for (int mi = 0; mi < 4; mi++)
        #pragma unroll
        for (int ni = 0; ni < 4; ni++)
          acc[mi][ni] = __builtin_amdgcn_mfma_f32_16x16x32_bf16(af[mi], bfr[ni], acc[mi][ni], 0, 0, 0);
    }
    __syncthreads();
  }

  int gn[4];
  #pragma unroll
  for (int ni = 0; ni < 4; ni++) gn[ni] = n0 + wc*64 + ni*16 + lo;

  if (EPI == 0){
    #pragma unroll
    for (int mi = 0; mi < 4; mi++){
      #pragma unroll
      for (int j = 0; j < 4; j++){
        int gr = rt*128 + wr*64 + mi*16 + hi*4 + j;
        if (gr < cntS){
          int atom = list[offS + gr];
          #pragma unroll
          for (int ni = 0; ni < 4; ni++)
            pout[((size_t)kh * NA + atom) * 512 + gn[ni]] = f2bf(acc[mi][ni][j]);
        }
      }
    }
  } else {
    float w3v[4];
    #pragma unroll
    for (int ni = 0; ni < 4; ni++) w3v[ni] = W3s[s * 512 + gn[ni]];
    float* pslot = pacc + (size_t)(x * 2 + wc) * NA;
    #pragma unroll
    for (int mi = 0; mi < 4; mi++){
      #pragma unroll
      for (int j = 0; j < 4; j++){
        int gr = rt*128 + wr*64 + mi*16 + hi*4 + j;
        if (gr < cntS){
          int atom = list[offS + gr];
          float pdot = 0.f;
          #pragma unroll
          for (int ni = 0; ni < 4; ni++)
            pdot += silu(acc[mi][ni][j]) * w3v[ni];
          pdot += __shfl_xor(pdot, 1, 16);
          pdot += __shfl_xor(pdot, 2, 16);
          pdot += __shfl_xor(pdot, 4, 16);
          pdot += __shfl_xor(pdot, 8, 16);
          if (lo == 0) pslot[atom] = pdot;
        }
      }
    }
  }
}

// ---------------- epilogue: combine 4 split-K partials + LN-affine + silu -> h1 -------
__global__ __launch_bounds__(256) void k_epi(
    const unsigned short* __restrict__ pbuf, const float* __restrict__ stats,
    const float* __restrict__ gW, const float* __restrict__ bW,
    const int* __restrict__ numbers, unsigned short* __restrict__ h1)
{
  int w = threadIdx.x >> 6, lane = threadIdx.x & 63;
  int atom = blockIdx.x * 4 + w;
  int s = numbers[atom];
  float mean = stats[2*atom], rstd = stats[2*atom+1];
  int c0 = lane * 8;
  u16x8 a0 = *reinterpret_cast<const u16x8*>(pbuf + (size_t)atom * 512 + c0);
  u16x8 a1 = *reinterpret_cast<const u16x8*>(pbuf + (size_t)(NA + atom) * 512 + c0);
  u16x8 a2 = *reinterpret_cast<const u16x8*>(pbuf + (size_t)(2*NA + atom) * 512 + c0);
  u16x8 a3 = *reinterpret_cast<const u16x8*>(pbuf + (size_t)(3*NA + atom) * 512 + c0);
  unsigned short o[8];
  #pragma unroll
  for (int j = 0; j < 8; j++){
    int c = c0 + j;
    float acc = (bf2f(a0[j]) + bf2f(a1[j])) + (bf2f(a2[j]) + bf2f(a3[j]));
    float vv = rstd * acc + bW[s*512 + c] - mean * rstd * gW[s*512 + c];
    o[j] = f2bf(silu(vv));
  }
  *reinterpret_cast<u16x8*>(h1 + (size_t)atom * 512 + c0) = *(const u16x8*)o;
}

// ---------------- final: sum 8 pacc partials/atom, wave-uniform molecule atomic -------
__global__ __launch_bounds__(256) void k_final2(
    const float* __restrict__ pacc, const int* __restrict__ numbers,
    const int* __restrict__ batch, const float* __restrict__ Wc,
    float* __restrict__ molOut)
{
  int atom = blockIdx.x * 256 + threadIdx.x;
  int lane = threadIdx.x & 63;
  float sum = 0.f;
  #pragma unroll
  for (int p = 0; p < 8; p++) sum += pacc[(size_t)p * NA + atom];
  float val = sum * (1.f / 128.f) + Wc[numbers[atom]];
  int mol = batch[atom];
  int m0 = __shfl(mol, 0, 64);
  int m63 = __shfl(mol, 63, 64);
  if (m0 == m63){
    #pragma unroll
    for (int m = 32; m; m >>= 1) val += __shfl_xor(val, m, 64);
    if (lane == 0) atomic_add_f(&molOut[mol], val);
  } else {
    atomic_add_f(&molOut[mol], val);
  }
}

extern "C" void kernel_launch(void* const* d_in, const int* in_sizes, int n_in,
                              void* d_out, int out_size, void* d_ws, size_t ws_size,
                              hipStream_t stream)
{
  const float* pos     = (const float*)d_in[0];
  const float* cells   = (const float*)d_in[1];
  const int*   numbers = (const int*)d_in[2];
  const int*   ei      = (const int*)d_in[3];
  const float* eoff    = (const float*)d_in[4];
  const int*   batch   = (const int*)d_in[5];
  const float* U       = (const float*)d_in[6];
  const float* gamma   = (const float*)d_in[7];
  const float* beta    = (const float*)d_in[8];
  const float* W1      = (const float*)d_in[9];
  const float* W2      = (const float*)d_in[10];
  const float* W3      = (const float*)d_in[11];
  const float* Wc      = (const float*)d_in[12];
  float* out = (float*)d_out;

  char* ws = (char*)d_ws;
  size_t off = 0;
  auto alloc = [&](size_t bytes) -> void* {
    void* p = ws + off;
    off += (bytes + 255) & ~(size_t)255;
    return p;
  };
  unsigned short* ps   = (unsigned short*)alloc((size_t)NA * FR * 2);      // 88 MB
  unsigned short* pbuf = (unsigned short*)alloc((size_t)4 * NA * 512 * 2); // 64 MB
  float* stats         = (float*)alloc((size_t)NA * 2 * 4);
  unsigned short* Wg1  = (unsigned short*)alloc((size_t)4 * 512 * FR * 2); // 11 MB
  unsigned short* W2t  = (unsigned short*)alloc((size_t)4 * 512 * 512 * 2);
  float* W3s           = (float*)alloc(4 * 512 * 4);
  unsigned short* h1   = (unsigned short*)alloc((size_t)NA * 512 * 2);
  float* pacc          = (float*)alloc((size_t)8 * NA * 4);
  int* list            = (int*)alloc(NA * 4);
  int* perm            = (int*)alloc((size_t)NE * 4);
  int* startsK         = (int*)alloc((65536 + 1) * 4);
  // contiguous zero-init region: cnt64k + gW + bW (one memset)
  int* cnt64k          = (int*)alloc(65536 * 4);
  float* gW            = (float*)alloc(4 * 512 * 4);
  float* bW            = (float*)alloc(4 * 512 * 4);
  int* cursor64k       = (int*)alloc(65536 * 4);
  int* bsum            = (int*)alloc(256 * 4);
  int* boff            = (int*)alloc(256 * 4);
  int* bhist           = (int*)alloc(64 * 4 * 4);
  int* boffs           = (int*)alloc(64 * 4 * 4);
  int* ints            = (int*)alloc(64);
  int* cnt = ints; int* offs = ints + 8;

  hipMemsetAsync(cnt64k, 0, 65536 * 4 + 2 * 4 * 512 * 4, stream);
  hipMemsetAsync(out, 0, (size_t)out_size * 4, stream);

  // edge hist (by recv*4+species) + atom hist, fused
  k_hist<<<2048 + 64, 256, 0, stream>>>(ei, numbers, cnt64k, bhist);
  k_scanA<<<256, 256, 0, stream>>>(cnt64k, bsum);
  k_scanB<<<1, 256, 0, stream>>>(bsum, boff, startsK, bhist, boffs, ints);
  k_scanC<<<256, 256, 0, stream>>>(cnt64k, boff, startsK, cursor64k);
  k_sortperm<<<NE / 256, 256, 0, stream>>>(ei, numbers, cursor64k, perm);
  k_aplace<<<NA / 256, 256, 0, stream>>>(numbers, boffs, list);

  // fused edge-accumulate + U-mix + 6-wave-split folded ps + Gram-form LN stats
  k_atom<<<NA, 384, 0, stream>>>(pos, cells, ei, eoff, batch, startsK, perm, U, ps, stats);

  // weight prep (single pass over W1; W2 mix + W3 mix fused)
  k_wg3<<<dim3(8, 42), 256, 0, stream>>>(W1, U, gamma, beta, Wg1, gW, bW);
  k_w2t<<<dim3(8, 8, 4), 256, 0, stream>>>(W2, U, W2t, W3, W3s);

  // GEMM1 split-K=4 (K=2688, 2176 blocks), then LN+silu epilogue
  k_gemm<0, 4><<<2176, 256, 0, stream>>>(ps, FR, FR, Wg1, list, offs, cnt,
                                         pbuf, nullptr, nullptr);
  k_epi<<<NA / 4, 256, 0, stream>>>(pbuf, stats, gW, bW, numbers, h1);

  // GEMM2 with fused silu + W3 dot -> per-atom partials (atomic-free)
  k_gemm<2, 1><<<544, 256, 0, stream>>>(h1, 512, 512, W2t, list, offs, cnt,
                                        nullptr, W3s, pacc);
  k_final2<<<NA / 256, 256, 0, stream>>>(pacc, numbers, batch, Wc, out);
}

// Round 19
// 310.484 us; speedup vs baseline: 1.0458x; 1.0023x over previous
//
#include <hip/hip_runtime.h>

#define NA   16384
#define NE   524288
#define NM   256
#define FF   4800
#define FR   2688   // folded K: 55 pair-blocks * 48 + 48 pad ; f' = b*48 + l*16 + qi*4 + pi
#define HH   512
#define NMX  10
#define NSPH 9

typedef __bf16 bf16x8 __attribute__((ext_vector_type(8)));
typedef float  f32x4  __attribute__((ext_vector_type(4)));
typedef unsigned short u16x8 __attribute__((ext_vector_type(8)));

__constant__ int g_ka[22] = {0, 1,1,1,2,2,3, 4,4,4,4,4, 5,5,5,5, 6,6,6, 7,7, 8};
__constant__ int g_kb[22] = {0, 1,2,3,2,3,3, 4,5,6,7,8, 5,6,7,8, 6,7,8, 7,8, 8};

__device__ inline unsigned short f2bf(float x){
  return __builtin_bit_cast(unsigned short, (__bf16)x);
}
__device__ inline float bf2f(unsigned short h){
  unsigned int u = ((unsigned int)h) << 16;
  return __builtin_bit_cast(float, u);
}
__device__ inline void atomic_add_f(float* p, float v){
  __hip_atomic_fetch_add(p, v, __ATOMIC_RELAXED, __HIP_MEMORY_SCOPE_AGENT);
}
__device__ inline void gload16(const void* g, void* l){
  __builtin_amdgcn_global_load_lds(
      (const __attribute__((address_space(1))) unsigned int*)g,
      (__attribute__((address_space(3))) unsigned int*)l, 16, 0, 0);
}
__device__ inline float silu(float x){ return x / (1.f + __expf(-x)); }

// decode pair-block b (0..54) -> (qb, pb), qb <= pb < 10
__device__ inline void decode_blk(int b, int& qb, int& pb){
  int q = 0, rem = b;
  while (rem >= 10 - q){ rem -= 10 - q; q++; }
  qb = q; pb = q + rem;
}

// full 4x4 pair block for one l (CNT components), outputs only
template<int CNT>
__device__ inline void ps_block(const float* __restrict__ cl, int qb, int pb, int off,
                                float nrm, bool diag, unsigned short* ob){
  float cq[4][CNT], cp[4][CNT];
  #pragma unroll
  for (int i = 0; i < 4; i++)
    #pragma unroll
    for (int k = 0; k < CNT; k++){
      cq[i][k] = cl[(qb*4 + i)*9 + off + k];
      cp[i][k] = cl[(pb*4 + i)*9 + off + k];
    }
  #pragma unroll
  for (int qi = 0; qi < 4; qi++)
    #pragma unroll
    for (int pi = 0; pi < 4; pi++){
      float v = 0.f;
      #pragma unroll
      for (int k = 0; k < CNT; k++) v += cq[qi][k] * cp[pi][k];
      v *= nrm;
      if (diag && qi > pi) v = 0.f;
      ob[qi*4 + pi] = f2bf(v);
    }
}

// half (2 qi rows x 4 pi) of a 4x4 pair block: 8 outputs, outputs only
template<int CNT>
__device__ inline void ps_block_half(const float* __restrict__ cl, int qb, int pb, int off,
                                     float nrm, bool diag, int qh, unsigned short* ob){
  float cq[2][CNT], cp[4][CNT];
  #pragma unroll
  for (int i = 0; i < 2; i++)
    #pragma unroll
    for (int k = 0; k < CNT; k++)
      cq[i][k] = cl[(qb*4 + qh*2 + i)*9 + off + k];
  #pragma unroll
  for (int i = 0; i < 4; i++)
    #pragma unroll
    for (int k = 0; k < CNT; k++)
      cp[i][k] = cl[(pb*4 + i)*9 + off + k];
  #pragma unroll
  for (int qi = 0; qi < 2; qi++)
    #pragma unroll
    for (int pi = 0; pi < 4; pi++){
      int qg = qh*2 + qi;
      float v = 0.f;
      #pragma unroll
      for (int k = 0; k < CNT; k++) v += cq[qi][k] * cp[pi][k];
      v *= nrm;
      if (diag && qg > pi) v = 0.f;
      ob[qi*4 + pi] = f2bf(v);
    }
}

__device__ inline int block_scan_excl(int v, int tid, int* lds){
  int lane = tid & 63, w = tid >> 6;
  int x = v;
  #pragma unroll
  for (int d = 1; d < 64; d <<= 1){
    int y = __shfl_up(x, d, 64);
    if (lane >= d) x += y;
  }
  if (lane == 63) lds[w] = x;
  __syncthreads();
  int wsum = 0;
  for (int i = 0; i < w; i++) wsum += lds[i];
  return wsum + x - v;
}

// ---------------- edge hist (2048 blocks) + atom hist (64 blocks), fused --------------
__global__ __launch_bounds__(256) void k_hist(const int* __restrict__ ei,
                                              const int* __restrict__ numbers,
                                              int* __restrict__ cnt64k,
                                              int* __restrict__ bhist){
  __shared__ int h[4];
  int blk = blockIdx.x, tid = threadIdx.x;
  if (blk < 2048){
    int e = blk * 256 + tid;
    int key = ei[NE + e] * 4 + numbers[ei[e]];
    atomicAdd(&cnt64k[key], 1);
  } else {
    if (tid < 4) h[tid] = 0;
    __syncthreads();
    atomicAdd(&h[numbers[(blk - 2048) * 256 + tid]], 1);
    __syncthreads();
    if (tid < 4) bhist[(blk - 2048) * 4 + tid] = h[tid];
  }
}

__global__ __launch_bounds__(256) void k_scanA(const int* __restrict__ cnt64k,
                                               int* __restrict__ bsum){
  __shared__ int lds[4];
  int tid = threadIdx.x;
  int v = cnt64k[blockIdx.x * 256 + tid];
  int lane = tid & 63;
  #pragma unroll
  for (int m = 32; m; m >>= 1) v += __shfl_xor(v, m, 64);
  if (lane == 0) lds[tid >> 6] = v;
  __syncthreads();
  if (tid == 0) bsum[blockIdx.x] = lds[0] + lds[1] + lds[2] + lds[3];
}

// scan of 256 block sums + atom-species offsets (fused serial tail)
__global__ __launch_bounds__(256) void k_scanB(const int* __restrict__ bsum,
                                               int* __restrict__ boff, int* __restrict__ starts,
                                               const int* __restrict__ bhist,
                                               int* __restrict__ boffs, int* __restrict__ ints){
  __shared__ int lds[4];
  int tid = threadIdx.x;
  int v = bsum[tid];
  int e = block_scan_excl(v, tid, lds);
  boff[tid] = e;
  if (tid == 0){
    starts[65536] = NE;
    int* cnt = ints; int* offs = ints + 8;
    int tot[4] = {0,0,0,0};
    for (int b = 0; b < 64; b++)
      for (int s = 0; s < 4; s++) tot[s] += bhist[b*4 + s];
    int o = 0;
    for (int s = 0; s < 4; s++){ cnt[s] = tot[s]; offs[s] = o; o += tot[s]; }
    offs[4] = o;
    int run[4];
    for (int s = 0; s < 4; s++) run[s] = offs[s];
    for (int b = 0; b < 64; b++)
      for (int s = 0; s < 4; s++){ boffs[b*4 + s] = run[s]; run[s] += bhist[b*4 + s]; }
  }
}

__global__ __launch_bounds__(256) void k_scanC(const int* __restrict__ cnt64k,
                                               const int* __restrict__ boff,
                                               int* __restrict__ starts, int* __restrict__ cursor){
  __shared__ int lds[4];
  int tid = threadIdx.x;
  int bin = blockIdx.x * 256 + tid;
  int v = cnt64k[bin];
  int e = block_scan_excl(v, tid, lds) + boff[blockIdx.x];
  starts[bin] = e;
  cursor[bin] = e;
}

__global__ __launch_bounds__(256) void k_sortperm(const int* __restrict__ ei,
                                                  const int* __restrict__ numbers,
                                                  int* __restrict__ cursor, int* __restrict__ perm){
  int e = blockIdx.x * 256 + threadIdx.x;
  if (e < NE){
    int key = ei[NE + e] * 4 + numbers[ei[e]];
    int p = atomicAdd(&cursor[key], 1);
    perm[p] = e;
  }
}

__global__ __launch_bounds__(256) void k_aplace(const int* __restrict__ numbers,
                                                const int* __restrict__ boffs,
                                                int* __restrict__ list){
  __shared__ int ws[4][4];
  int tid = threadIdx.x, w = tid >> 6, lane = tid & 63;
  int i = blockIdx.x * 256 + tid;
  int sp = numbers[i];
  int rank = 0;
  #pragma unroll
  for (int s = 0; s < 4; s++){
    unsigned long long m = __ballot(sp == s);
    if (s == sp) rank = __popcll(m & (((unsigned long long)1 << lane) - 1));
    if (lane == 0) ws[w][s] = __popcll(m);
  }
  __syncthreads();
  int pre = 0;
  for (int w2 = 0; w2 < w; w2++) pre += ws[w2][sp];
  list[boffs[blockIdx.x * 4 + sp] + pre + rank] = i;
}

// ---------------- fused per-atom: 2-step wave-parallel geometry -> accumulate ->
//                  U-mix -> ps (6-wave) + Gram stats ----------------------------------
__global__ __launch_bounds__(384) void k_atom(
    const float* __restrict__ pos, const float* __restrict__ cells,
    const int* __restrict__ ei, const float* __restrict__ eoff,
    const int* __restrict__ batch, const int* __restrict__ startsK,
    const int* __restrict__ perm, const float* __restrict__ U,
    unsigned short* __restrict__ ps, float* __restrict__ stats)
{
  __shared__ float rf[64][7];     // r, fc, hx, hy, hz (stride 7 -> conflict-free)
  __shared__ float Rl[64][11];    // stride 11 -> conflict-free writes
  __shared__ float Yl[64][NSPH];
  __shared__ float csr[360];
  __shared__ float cl[360];
  __shared__ float ul[16];
  int atom = blockIdx.x;
  int tid = threadIdx.x;
  if (tid < 16) ul[tid] = U[tid];
  int e0 = startsK[atom * 4], e1 = startsK[atom * 4 + 4];
  float px = pos[atom*3+0], py = pos[atom*3+1], pz = pos[atom*3+2];
  int sp = tid / 90, n = (tid % 90) / 9, k = tid % 9;
  int aS = 0, aE = 0;
  if (tid < 360){ aS = startsK[atom * 4 + sp]; aE = startsK[atom * 4 + sp + 1]; }
  float acc = 0.f;
  for (int base = e0; base < e1; base += 64){
    int nch = min(64, e1 - base);
    // step 1: wave 0 computes r, fc, unit vector
    if (tid < nch){
      int e = perm[base + tid];
      int snd = ei[e];
      const float* C = cells + (size_t)batch[snd] * 9;
      float o0 = eoff[e*3+0], o1 = eoff[e*3+1], o2 = eoff[e*3+2];
      float rx = px - pos[snd*3+0] + o0*C[0] + o1*C[3] + o2*C[6];
      float ry = py - pos[snd*3+1] + o0*C[1] + o1*C[4] + o2*C[7];
      float rz = pz - pos[snd*3+2] + o0*C[2] + o1*C[5] + o2*C[8];
      float r = sqrtf(rx*rx + ry*ry + rz*rz + 1e-12f);
      float inv = 1.f / r;
      float fc = (r < 5.f) ? (0.5f * (__cosf(r * 0.6283185307179586f) + 1.f)) : 0.f;
      rf[tid][0] = r;
      rf[tid][1] = fc;
      rf[tid][2] = rx * inv;
      rf[tid][3] = ry * inv;
      rf[tid][4] = rz * inv;
    }
    __syncthreads();
    // step 2: component-parallel R/Y across all 6 waves
    {
      int w6 = tid >> 6, e = tid & 63;
      if (e < nch){
        if (w6 < 5){
          float r = rf[e][0], fc = rf[e][1];
          #pragma unroll
          for (int t = 0; t < 2; t++){
            int nn = w6 * 2 + t;
            float d = r - (5.f/9.f) * (float)nn;
            Rl[e][nn] = __expf(-2.f * d * d) * fc;
          }
        } else {
          float hx = rf[e][2], hy = rf[e][3], hz = rf[e][4];
          Yl[e][0] = 0.28209479177387814f;
          Yl[e][1] = 0.4886025119029199f * hy;
          Yl[e][2] = 0.4886025119029199f * hz;
          Yl[e][3] = 0.4886025119029199f * hx;
          Yl[e][4] = 1.0925484305920792f * hx * hy;
          Yl[e][5] = 1.0925484305920792f * hy * hz;
          Yl[e][6] = 0.31539156525252005f * (3.f * hz * hz - 1.f);
          Yl[e][7] = 1.0925484305920792f * hx * hz;
          Yl[e][8] = 0.5462742152960396f * (hx * hx - hy * hy);
        }
      }
    }
    __syncthreads();
    if (tid < 360){
      int lo2 = max(aS, base), hi2 = min(aE, base + nch);
      for (int e = lo2; e < hi2; e++){
        int j = e - base;
        acc += Rl[j][n] * Yl[j][k];
      }
    }
    __syncthreads();
  }
  if (tid < 360) csr[tid] = acc;
  __syncthreads();
  if (tid < 360){
    int a = tid / 90, nk = tid % 90;
    cl[tid] = ul[a*4+0]*csr[nk] + ul[a*4+1]*csr[90+nk]
            + ul[a*4+2]*csr[180+nk] + ul[a*4+3]*csr[270+nk];
  }
  __syncthreads();
  // ps: w0/w1 -> l=2 halves, w2/w3 -> l=1 halves, w4 -> l=0 full, w5 -> pad + Gram stats
  int w6 = tid >> 6, b = tid & 63;
  if (w6 <= 3 && b < 55){
    int l = (w6 < 2) ? 2 : 1;
    int qh = w6 & 1;
    int qb, pb;
    decode_blk(b, qb, pb);
    bool diag = (qb == pb);
    unsigned short ob[8];
    if (l == 2) ps_block_half<5>(cl, qb, pb, 4, 0.4472135954999579f, diag, qh, ob);
    else        ps_block_half<3>(cl, qb, pb, 1, 0.5773502691896258f, diag, qh, ob);
    unsigned short* dst = ps + (size_t)atom * FR + b * 48 + l * 16 + qh * 8;
    *reinterpret_cast<u16x8*>(dst) = *(const u16x8*)ob;
  } else if (w6 == 4 && b < 55){
    int qb, pb;
    decode_blk(b, qb, pb);
    bool diag = (qb == pb);
    unsigned short ob[16];
    ps_block<1>(cl, qb, pb, 0, 1.f, diag, ob);
    unsigned short* dst = ps + (size_t)atom * FR + b * 48;
    *reinterpret_cast<u16x8*>(dst)     = *(const u16x8*)&ob[0];
    *reinterpret_cast<u16x8*>(dst + 8) = *(const u16x8*)&ob[8];
  } else if (w6 == 5){
    if (b < 6){
      unsigned short zb[8] = {0,0,0,0,0,0,0,0};
      *reinterpret_cast<u16x8*>(ps + (size_t)atom * FR + 2640 + b * 8) = *(const u16x8*)zb;
    }
    // LN stats via closed form:
    //   s1 = sum_l nrm_l * sum_{k in l} S[k]^2,  S[k] = sum_q cl[q][k]
    //   s2 = sum_l nrm_l^2 * sum_{k,k' in l} G[k,k']^2,  G = sum_q cl[q][k]*cl[q][k']
    float c1 = 0.f, c2 = 0.f;
    if (b >= 8 && b < 17){
      int kk = b - 8;
      float S = 0.f;
      for (int q = 0; q < 40; q++) S += cl[q*9 + kk];
      float nrm = (kk == 0) ? 1.f : ((kk < 4) ? 0.5773502691896258f : 0.4472135954999579f);
      c1 = nrm * S * S;
    } else if (b >= 24 && b < 46){
      int j = b - 24;
      int ka = g_ka[j], kb = g_kb[j];
      float G = 0.f;
      for (int q = 0; q < 40; q++) G += cl[q*9 + ka] * cl[q*9 + kb];
      float n2 = (ka == 0) ? 1.f : ((ka < 4) ? (1.f/3.f) : 0.2f);
      float mul = (ka == kb) ? 1.f : 2.f;
      c2 = n2 * mul * G * G;
    }
    #pragma unroll
    for (int m = 32; m; m >>= 1){ c1 += __shfl_xor(c1, m, 64); c2 += __shfl_xor(c2, m, 64); }
    if (b == 0){
      float mean = c1 * (1.f / FF);
      float var = c2 * (1.f / FF) - mean * mean;
      var = fmaxf(var, 0.f);
      stats[2*atom]   = mean;
      stats[2*atom+1] = rsqrtf(var + 1e-5f);
    }
  }
}

// ---------------- weight prep v3: SINGLE pass over W1, all 4 species at once ----------
__global__ __launch_bounds__(256) void k_wg3(
    const float* __restrict__ W1, const float* __restrict__ U,
    const float* __restrict__ gamma, const float* __restrict__ beta,
    unsigned short* __restrict__ Wg, float* __restrict__ gW, float* __restrict__ bW)
{
  __shared__ unsigned short og[4][64][64]; // [s][fi][ni], 32 KB
  int n0 = blockIdx.x * 64, f0 = blockIdx.y * 64;
  int tid = threadIdx.x, ni = tid & 63;
  float u[4][4];
  #pragma unroll
  for (int a = 0; a < 4; a++)
    #pragma unroll
    for (int s = 0; s < 4; s++) u[a][s] = U[a*4 + s];
  float gs[4] = {0,0,0,0}, bs[4] = {0,0,0,0};
  for (int rep = 0; rep < 16; rep++){
    int fi = rep * 4 + (tid >> 6);
    int fp = f0 + fi;
    int b = fp / 48, r = fp % 48;
    int l = r >> 4, qi = (r >> 2) & 3, pi = r & 3;
    float tg[4] = {0,0,0,0}, tb[4] = {0,0,0,0};
    if (b < 55){
      int qb, pb;
      decode_blk(b, qb, pb);
      bool zero = (qb == pb) && (qi > pi);
      if (!zero){
        int q = qb*4 + qi, p = pb*4 + pi;
        int fa = (q * 40 + p) * 3 + l;
        float ga = gamma[fa], ba = beta[fa];
        float wm[4] = {0,0,0,0};
        #pragma unroll
        for (int a = 0; a < 4; a++){
          float wa = W1[(size_t)a * FF * 512 + (size_t)fa * 512 + n0 + ni];
          #pragma unroll
          for (int s = 0; s < 4; s++) wm[s] += u[a][s] * wa;
        }
        #pragma unroll
        for (int s = 0; s < 4; s++){ tg[s] = ga * wm[s]; tb[s] = ba * wm[s]; }
        if (p != q){
          int fb = (p * 40 + q) * 3 + l;
          float gb = gamma[fb], bb = beta[fb];
          float wn[4] = {0,0,0,0};
          #pragma unroll
          for (int a = 0; a < 4; a++){
            float wb = W1[(size_t)a * FF * 512 + (size_t)fb * 512 + n0 + ni];
            #pragma unroll
            for (int s = 0; s < 4; s++) wn[s] += u[a][s] * wb;
          }
          #pragma unroll
          for (int s = 0; s < 4; s++){ tg[s] += gb * wn[s]; tb[s] += bb * wn[s]; }
        }
      }
    }
    #pragma unroll
    for (int s = 0; s < 4; s++){
      og[s][fi][ni] = f2bf(tg[s]);
      gs[s] += tg[s];
      bs[s] += tb[s];
    }
  }
  #pragma unroll
  for (int s = 0; s < 4; s++){
    atomic_add_f(&gW[s * 512 + n0 + ni], gs[s]);
    atomic_add_f(&bW[s * 512 + n0 + ni], bs[s]);
  }
  __syncthreads();
  for (int it = 0; it < 8; it++){
    int idx = it * 256 + tid;      // 2048 u16x8 chunks: [s][nn][c]
    int c = idx & 7;
    int rrow = idx >> 3;
    int s = rrow >> 6, nn = rrow & 63;
    unsigned short o[8];
    #pragma unroll
    for (int j = 0; j < 8; j++) o[j] = og[s][c*8 + j][nn];
    *reinterpret_cast<u16x8*>(&Wg[((size_t)s * 512 + n0 + nn) * FR + f0 + c * 8]) = *(const u16x8*)o;
  }
}

// W2 mix (+ W3s slice computed by the x==0,y==0 block of each species)
__global__ __launch_bounds__(256) void k_w2t(
    const float* __restrict__ W2, const float* __restrict__ U,
    unsigned short* __restrict__ W2t,
    const float* __restrict__ W3, float* __restrict__ W3s)
{
  __shared__ float t[64][65];
  int n0 = blockIdx.x * 64, k0 = blockIdx.y * 64, s = blockIdx.z;
  float u0 = U[s], u1 = U[4+s], u2 = U[8+s], u3 = U[12+s];
  int tid = threadIdx.x;
  if (blockIdx.x == 0 && blockIdx.y == 0){
    for (int k = tid; k < 512; k += 256)
      W3s[s*512 + k] = u0*W3[k] + u1*W3[512+k] + u2*W3[2*512+k] + u3*W3[3*512+k];
  }
  #pragma unroll 4
  for (int rep = 0; rep < 16; rep++){
    int idx = rep * 256 + tid;
    int ki = idx >> 6, ni = idx & 63;
    size_t base = (size_t)(k0 + ki) * 512 + (n0 + ni);
    t[ki][ni] = u0*W2[base] + u1*W2[base + 512*512]
              + u2*W2[base + 2*512*512] + u3*W2[base + 3*512*512];
  }
  __syncthreads();
  #pragma unroll 4
  for (int rep = 0; rep < 16; rep++){
    int idx = rep * 256 + tid;
    int ni = idx >> 6, ki = idx & 63;
    W2t[((size_t)s * 512 + n0 + ni) * 512 + k0 + ki] = f2bf(t[ki][ni]);
  }
}

// ---------------- GEMM template (128x128 tile, BK=64, bf16 MFMA) ----------------
template<int EPI, int NSPLIT>
__global__ __launch_bounds__(256) void k_gemm(
    const unsigned short* __restrict__ Ag, int lda, int K,
    const unsigned short* __restrict__ Btg,
    const int* __restrict__ list, const int* __restrict__ offs, const int* __restrict__ cnt,
    unsigned short* __restrict__ pout,
    const float* __restrict__ W3s, float* __restrict__ pacc)
{
  __shared__ alignas(16) char smem[32768];
  const int NV = 4 * NSPLIT;
  int b = blockIdx.x;
  int y = (b & 7) + 8 * (b / (8 * NV));
  int v = (b >> 3) % NV;
  int x = v & 3, kh = v >> 2;

  int s = 0, t = y;
  for (; s < 4; s++){
    int nts = (cnt[s] + 127) >> 7;
    if (t < nts) break;
    t -= nts;
  }
  if (s >= 4) return;
  int cntS = cnt[s], offS = offs[s];
  int rt = t, n0 = x * 128;
  int tid = threadIdx.x, w = tid >> 6, lane = tid & 63;
  int wr = w >> 1, wc = w & 1;

  const unsigned short* Bts = Btg + (size_t)s * 512 * K;
  const unsigned short* gA[4];
  const unsigned short* gB[4];
  char* lA[4];
  char* lB[4];
  #pragma unroll
  for (int it = 0; it < 4; it++){
    int g = it * 4 + w;
    int idx = g * 64 + lane;
    int row = idx >> 3, ch = idx & 7;
    int cg = ch ^ (row & 7);
    int gr = rt * 128 + row; gr = gr < cntS ? gr : cntS - 1;
    int atom = list[offS + gr];
    gA[it] = Ag + (size_t)atom * lda + cg * 8;
    lA[it] = smem + g * 1024;
    gB[it] = Bts + (size_t)(n0 + row) * K + cg * 8;
    lB[it] = smem + 16384 + g * 1024;
  }

  int hi = lane >> 4, lo = lane & 15;
  f32x4 acc[4][4];
  #pragma unroll
  for (int mi = 0; mi < 4; mi++)
    #pragma unroll
    for (int ni = 0; ni < 4; ni++)
      #pragma unroll
      for (int r = 0; r < 4; r++) acc[mi][ni][r] = 0.f;

  int abase[4], a7[4], bbase[4], b7[4];
  #pragma unroll
  for (int mi = 0; mi < 4; mi++){ int row = wr*64 + mi*16 + lo; abase[mi] = row*128; a7[mi] = row & 7; }
  #pragma unroll
  for (int ni = 0; ni < 4; ni++){ int row = wc*64 + ni*16 + lo; bbase[ni] = 16384 + row*128; b7[ni] = row & 7; }

  int nk = K / 64;
  int k0 = ((nk * kh) / NSPLIT) * 64;
  int k1 = ((nk * (kh + 1)) / NSPLIT) * 64;

  for (int kt = k0; kt < k1; kt += 64){
    #pragma unroll
    for (int it = 0; it < 4; it++) gload16(gA[it] + kt, lA[it]);
    #pragma unroll
    for (int it = 0; it < 4; it++) gload16(gB[it] + kt, lB[it]);
    __syncthreads();
    #pragma unroll
    for (int kk = 0; kk < 2; kk++){
      bf16x8 af[4], bfr[4];
      #pragma unroll
      for (int mi = 0; mi < 4; mi++)
        af[mi] = *(const bf16x8*)(smem + abase[mi] + (((kk*4 + hi) ^ a7[mi]) << 4));
      #pragma unroll
      for (int ni = 0; ni < 4; ni++)
        bfr[ni] = *(const bf16x8*)(smem + bbase[ni] + (((kk*4 + hi) ^ b7[ni]) << 4));
      #pragma unroll
      for (int mi = 0; mi < 4; mi++)
        #pragma unroll
        for (int ni = 0; ni < 4; ni++)
          acc[mi][ni] = __builtin_amdgcn_mfma_f32_16x16x32_bf16(af[mi], bfr[ni], acc[mi][ni], 0, 0, 0);
    }
    __syncthreads();
  }

  int gn[4];
  #pragma unroll
  for (int ni = 0; ni < 4; ni++) gn[ni] = n0 + wc*64 + ni*16 + lo;

  if (EPI == 0){
    #pragma unroll
    for (int mi = 0; mi < 4; mi++){
      #pragma unroll
      for (int j = 0; j < 4; j++){
        int gr = rt*128 + wr*64 + mi*16 + hi*4 + j;
        if (gr < cntS){
          int atom = list[offS + gr];
          #pragma unroll
          for (int ni = 0; ni < 4; ni++)
            pout[((size_t)kh * NA + atom) * 512 + gn[ni]] = f2bf(acc[mi][ni][j]);
        }
      }
    }
  } else {
    float w3v[4];
    #pragma unroll
    for (int ni = 0; ni < 4; ni++) w3v[ni] = W3s[s * 512 + gn[ni]];
    float* pslot = pacc + (size_t)(x * 2 + wc) * NA;
    #pragma unroll
    for (int mi = 0; mi < 4; mi++){
      #pragma unroll
      for (int j = 0; j < 4; j++){
        int gr = rt*128 + wr*64 + mi*16 + hi*4 + j;
        if (gr < cntS){
          int atom = list[offS + gr];
          float pdot = 0.f;
          #pragma unroll
          for (int ni = 0; ni < 4; ni++)
            pdot += silu(acc[mi][ni][j]) * w3v[ni];
          pdot += __shfl_xor(pdot, 1, 16);
          pdot += __shfl_xor(pdot, 2, 16);
          pdot += __shfl_xor(pdot, 4, 16);
          pdot += __shfl_xor(pdot, 8, 16);
          if (lo == 0) pslot[atom] = pdot;
        }
      }
    }
  }
}

// ---------------- epilogue: combine 4 split-K partials + LN-affine + silu -> h1 -------
__global__ __launch_bounds__(256) void k_epi(
    const unsigned short* __restrict__ pbuf, const float* __restrict__ stats,
    const float* __restrict__ gW, const float* __restrict__ bW,
    const int* __restrict__ numbers, unsigned short* __restrict__ h1)
{
  int w = threadIdx.x >> 6, lane = threadIdx.x & 63;
  int atom = blockIdx.x * 4 + w;
  int s = numbers[atom];
  float mean = stats[2*atom], rstd = stats[2*atom+1];
  int c0 = lane * 8;
  u16x8 a0 = *reinterpret_cast<const u16x8*>(pbuf + (size_t)atom * 512 + c0);
  u16x8 a1 = *reinterpret_cast<const u16x8*>(pbuf + (size_t)(NA + atom) * 512 + c0);
  u16x8 a2 = *reinterpret_cast<const u16x8*>(pbuf + (size_t)(2*NA + atom) * 512 + c0);
  u16x8 a3 = *reinterpret_cast<const u16x8*>(pbuf + (size_t)(3*NA + atom) * 512 + c0);
  unsigned short o[8];
  #pragma unroll
  for (int j = 0; j < 8; j++){
    int c = c0 + j;
    float acc = (bf2f(a0[j]) + bf2f(a1[j])) + (bf2f(a2[j]) + bf2f(a3[j]));
    float vv = rstd * acc + bW[s*512 + c] - mean * rstd * gW[s*512 + c];
    o[j] = f2bf(silu(vv));
  }
  *reinterpret_cast<u16x8*>(h1 + (size_t)atom * 512 + c0) = *(const u16x8*)o;
}

// ---------------- final: sum 8 pacc partials/atom, wave-uniform molecule atomic -------
__global__ __launch_bounds__(256) void k_final2(
    const float* __restrict__ pacc, const int* __restrict__ numbers,
    const int* __restrict__ batch, const float* __restrict__ Wc,
    float* __restrict__ molOut)
{
  int atom = blockIdx.x * 256 + threadIdx.x;
  int lane = threadIdx.x & 63;
  float sum = 0.f;
  #pragma unroll
  for (int p = 0; p < 8; p++) sum += pacc[(size_t)p * NA + atom];
  float val = sum * (1.f / 128.f) + Wc[numbers[atom]];
  int mol = batch[atom];
  int m0 = __shfl(mol, 0, 64);
  int m63 = __shfl(mol, 63, 64);
  if (m0 == m63){
    #pragma unroll
    for (int m = 32; m; m >>= 1) val += __shfl_xor(val, m, 64);
    if (lane == 0) atomic_add_f(&molOut[mol], val);
  } else {
    atomic_add_f(&molOut[mol], val);
  }
}

extern "C" void kernel_launch(void* const* d_in, const int* in_sizes, int n_in,
                              void* d_out, int out_size, void* d_ws, size_t ws_size,
                              hipStream_t stream)
{
  const float* pos     = (const float*)d_in[0];
  const float* cells   = (const float*)d_in[1];
  const int*   numbers = (const int*)d_in[2];
  const int*   ei      = (const int*)d_in[3];
  const float* eoff    = (const float*)d_in[4];
  const int*   batch   = (const int*)d_in[5];
  const float* U       = (const float*)d_in[6];
  const float* gamma   = (const float*)d_in[7];
  const float* beta    = (const float*)d_in[8];
  const float* W1      = (const float*)d_in[9];
  const float* W2      = (const float*)d_in[10];
  const float* W3      = (const float*)d_in[11];
  const float* Wc      = (const float*)d_in[12];
  float* out = (float*)d_out;

  char* ws = (char*)d_ws;
  size_t off = 0;
  auto alloc = [&](size_t bytes) -> void* {
    void* p = ws + off;
    off += (bytes + 255) & ~(size_t)255;
    return p;
  };
  unsigned short* ps   = (unsigned short*)alloc((size_t)NA * FR * 2);      // 88 MB
  unsigned short* pbuf = (unsigned short*)alloc((size_t)4 * NA * 512 * 2); // 64 MB
  float* stats         = (float*)alloc((size_t)NA * 2 * 4);
  unsigned short* Wg1  = (unsigned short*)alloc((size_t)4 * 512 * FR * 2); // 11 MB
  unsigned short* W2t  = (unsigned short*)alloc((size_t)4 * 512 * 512 * 2);
  float* W3s           = (float*)alloc(4 * 512 * 4);
  unsigned short* h1   = (unsigned short*)alloc((size_t)NA * 512 * 2);
  float* pacc          = (float*)alloc((size_t)8 * NA * 4);
  int* list            = (int*)alloc(NA * 4);
  int* perm            = (int*)alloc((size_t)NE * 4);
  int* startsK         = (int*)alloc((65536 + 1) * 4);
  // contiguous zero-init region: cnt64k + gW + bW (one memset)
  int* cnt64k          = (int*)alloc(65536 * 4);
  float* gW            = (float*)alloc(4 * 512 * 4);
  float* bW            = (float*)alloc(4 * 512 * 4);
  int* cursor64k       = (int*)alloc(65536 * 4);
  int* bsum            = (int*)alloc(256 * 4);
  int* boff            = (int*)alloc(256 * 4);
  int* bhist           = (int*)alloc(64 * 4 * 4);
  int* boffs           = (int*)alloc(64 * 4 * 4);
  int* ints            = (int*)alloc(64);
  int* cnt = ints; int* offs = ints + 8;

  hipMemsetAsync(cnt64k, 0, 65536 * 4 + 2 * 4 * 512 * 4, stream);
  hipMemsetAsync(out, 0, (size_t)out_size * 4, stream);

  // edge hist (by recv*4+species) + atom hist, fused
  k_hist<<<2048 + 64, 256, 0, stream>>>(ei, numbers, cnt64k, bhist);
  k_scanA<<<256, 256, 0, stream>>>(cnt64k, bsum);
  k_scanB<<<1, 256, 0, stream>>>(bsum, boff, startsK, bhist, boffs, ints);
  k_scanC<<<256, 256, 0, stream>>>(cnt64k, boff, startsK, cursor64k);
  k_sortperm<<<NE / 256, 256, 0, stream>>>(ei, numbers, cursor64k, perm);
  k_aplace<<<NA / 256, 256, 0, stream>>>(numbers, boffs, list);

  // fused per-atom pipeline (wave-parallel geometry, 6-wave ps, Gram stats)
  k_atom<<<NA, 384, 0, stream>>>(pos, cells, ei, eoff, batch, startsK, perm, U, ps, stats);

  // weight prep (single pass over W1; W2 mix + W3 mix fused)
  k_wg3<<<dim3(8, 42), 256, 0, stream>>>(W1, U, gamma, beta, Wg1, gW, bW);
  k_w2t<<<dim3(8, 8, 4), 256, 0, stream>>>(W2, U, W2t, W3, W3s);

  // GEMM1 split-K=4 (K=2688, 2176 blocks), then LN+silu epilogue
  k_gemm<0, 4><<<2176, 256, 0, stream>>>(ps, FR, FR, Wg1, list, offs, cnt,
                                         pbuf, nullptr, nullptr);
  k_epi<<<NA / 4, 256, 0, stream>>>(pbuf, stats, gW, bW, numbers, h1);

  // GEMM2 with fused silu + W3 dot -> per-atom partials (atomic-free)
  k_gemm<2, 1><<<544, 256, 0, stream>>>(h1, 512, 512, W2t, list, offs, cnt,
                                        nullptr, W3s, pacc);
  k_final2<<<NA / 256, 256, 0, stream>>>(pacc, numbers, batch, Wc, out);
}

// Round 20
// 304.674 us; speedup vs baseline: 1.0657x; 1.0191x over previous
//
#include <hip/hip_runtime.h>

#define NA   16384
#define NE   524288
#define NM   256
#define FF   4800
#define FR   2688   // folded K: 55 pair-blocks * 48 + 48 pad ; f' = b*48 + l*16 + qi*4 + pi
#define HH   512
#define NMX  10
#define NSPH 9

typedef __bf16 bf16x8 __attribute__((ext_vector_type(8)));
typedef float  f32x4  __attribute__((ext_vector_type(4)));
typedef unsigned short u16x8 __attribute__((ext_vector_type(8)));

__constant__ int g_ka[22] = {0, 1,1,1,2,2,3, 4,4,4,4,4, 5,5,5,5, 6,6,6, 7,7, 8};
__constant__ int g_kb[22] = {0, 1,2,3,2,3,3, 4,5,6,7,8, 5,6,7,8, 6,7,8, 7,8, 8};

__device__ inline unsigned short f2bf(float x){
  return __builtin_bit_cast(unsigned short, (__bf16)x);
}
__device__ inline float bf2f(unsigned short h){
  unsigned int u = ((unsigned int)h) << 16;
  return __builtin_bit_cast(float, u);
}
__device__ inline void atomic_add_f(float* p, float v){
  __hip_atomic_fetch_add(p, v, __ATOMIC_RELAXED, __HIP_MEMORY_SCOPE_AGENT);
}
__device__ inline void gload16(const void* g, void* l){
  __builtin_amdgcn_global_load_lds(
      (const __attribute__((address_space(1))) unsigned int*)g,
      (__attribute__((address_space(3))) unsigned int*)l, 16, 0, 0);
}
__device__ inline float silu(float x){ return x / (1.f + __expf(-x)); }

// decode pair-block b (0..54) -> (qb, pb), qb <= pb < 10
__device__ inline void decode_blk(int b, int& qb, int& pb){
  int q = 0, rem = b;
  while (rem >= 10 - q){ rem -= 10 - q; q++; }
  qb = q; pb = q + rem;
}

// full 4x4 pair block for one l (CNT components), outputs only
template<int CNT>
__device__ inline void ps_block(const float* __restrict__ cl, int qb, int pb, int off,
                                float nrm, bool diag, unsigned short* ob){
  float cq[4][CNT], cp[4][CNT];
  #pragma unroll
  for (int i = 0; i < 4; i++)
    #pragma unroll
    for (int k = 0; k < CNT; k++){
      cq[i][k] = cl[(qb*4 + i)*9 + off + k];
      cp[i][k] = cl[(pb*4 + i)*9 + off + k];
    }
  #pragma unroll
  for (int qi = 0; qi < 4; qi++)
    #pragma unroll
    for (int pi = 0; pi < 4; pi++){
      float v = 0.f;
      #pragma unroll
      for (int k = 0; k < CNT; k++) v += cq[qi][k] * cp[pi][k];
      v *= nrm;
      if (diag && qi > pi) v = 0.f;
      ob[qi*4 + pi] = f2bf(v);
    }
}

// half (2 qi rows x 4 pi) of a 4x4 pair block: 8 outputs, outputs only
template<int CNT>
__device__ inline void ps_block_half(const float* __restrict__ cl, int qb, int pb, int off,
                                     float nrm, bool diag, int qh, unsigned short* ob){
  float cq[2][CNT], cp[4][CNT];
  #pragma unroll
  for (int i = 0; i < 2; i++)
    #pragma unroll
    for (int k = 0; k < CNT; k++)
      cq[i][k] = cl[(qb*4 + qh*2 + i)*9 + off + k];
  #pragma unroll
  for (int i = 0; i < 4; i++)
    #pragma unroll
    for (int k = 0; k < CNT; k++)
      cp[i][k] = cl[(pb*4 + i)*9 + off + k];
  #pragma unroll
  for (int qi = 0; qi < 2; qi++)
    #pragma unroll
    for (int pi = 0; pi < 4; pi++){
      int qg = qh*2 + qi;
      float v = 0.f;
      #pragma unroll
      for (int k = 0; k < CNT; k++) v += cq[qi][k] * cp[pi][k];
      v *= nrm;
      if (diag && qg > pi) v = 0.f;
      ob[qi*4 + pi] = f2bf(v);
    }
}

__device__ inline int block_scan_excl(int v, int tid, int* lds){
  int lane = tid & 63, w = tid >> 6;
  int x = v;
  #pragma unroll
  for (int d = 1; d < 64; d <<= 1){
    int y = __shfl_up(x, d, 64);
    if (lane >= d) x += y;
  }
  if (lane == 63) lds[w] = x;
  __syncthreads();
  int wsum = 0;
  for (int i = 0; i < w; i++) wsum += lds[i];
  return wsum + x - v;
}

// ---------------- edge hist (2048 blocks) + atom hist (64 blocks), fused --------------
__global__ __launch_bounds__(256) void k_hist(const int* __restrict__ ei,
                                              const int* __restrict__ numbers,
                                              int* __restrict__ cnt64k,
                                              int* __restrict__ bhist){
  __shared__ int h[4];
  int blk = blockIdx.x, tid = threadIdx.x;
  if (blk < 2048){
    int e = blk * 256 + tid;
    int key = ei[NE + e] * 4 + numbers[ei[e]];
    atomicAdd(&cnt64k[key], 1);
  } else {
    if (tid < 4) h[tid] = 0;
    __syncthreads();
    atomicAdd(&h[numbers[(blk - 2048) * 256 + tid]], 1);
    __syncthreads();
    if (tid < 4) bhist[(blk - 2048) * 4 + tid] = h[tid];
  }
}

__global__ __launch_bounds__(256) void k_scanA(const int* __restrict__ cnt64k,
                                               int* __restrict__ bsum){
  __shared__ int lds[4];
  int tid = threadIdx.x;
  int v = cnt64k[blockIdx.x * 256 + tid];
  int lane = tid & 63;
  #pragma unroll
  for (int m = 32; m; m >>= 1) v += __shfl_xor(v, m, 64);
  if (lane == 0) lds[tid >> 6] = v;
  __syncthreads();
  if (tid == 0) bsum[blockIdx.x] = lds[0] + lds[1] + lds[2] + lds[3];
}

// scan of 256 block sums + atom-species offsets (fused serial tail)
__global__ __launch_bounds__(256) void k_scanB(const int* __restrict__ bsum,
                                               int* __restrict__ boff, int* __restrict__ starts,
                                               const int* __restrict__ bhist,
                                               int* __restrict__ boffs, int* __restrict__ ints){
  __shared__ int lds[4];
  int tid = threadIdx.x;
  int v = bsum[tid];
  int e = block_scan_excl(v, tid, lds);
  boff[tid] = e;
  if (tid == 0){
    starts[65536] = NE;
    int* cnt = ints; int* offs = ints + 8;
    int tot[4] = {0,0,0,0};
    for (int b = 0; b < 64; b++)
      for (int s = 0; s < 4; s++) tot[s] += bhist[b*4 + s];
    int o = 0;
    for (int s = 0; s < 4; s++){ cnt[s] = tot[s]; offs[s] = o; o += tot[s]; }
    offs[4] = o;
    int run[4];
    for (int s = 0; s < 4; s++) run[s] = offs[s];
    for (int b = 0; b < 64; b++)
      for (int s = 0; s < 4; s++){ boffs[b*4 + s] = run[s]; run[s] += bhist[b*4 + s]; }
  }
}

__global__ __launch_bounds__(256) void k_scanC(const int* __restrict__ cnt64k,
                                               const int* __restrict__ boff,
                                               int* __restrict__ starts, int* __restrict__ cursor){
  __shared__ int lds[4];
  int tid = threadIdx.x;
  int bin = blockIdx.x * 256 + tid;
  int v = cnt64k[bin];
  int e = block_scan_excl(v, tid, lds) + boff[blockIdx.x];
  starts[bin] = e;
  cursor[bin] = e;
}

// sort + pack: epack[p] = {snd_bits, (o.C)x, (o.C)y, (o.C)z} (coalesced reads,
// one scattered 16B write -> removes 3 dependent gathers from k_atom)
__global__ __launch_bounds__(256) void k_sortpack(const int* __restrict__ ei,
                                                  const int* __restrict__ numbers,
                                                  const float* __restrict__ eoff,
                                                  const float* __restrict__ cells,
                                                  const int* __restrict__ batch,
                                                  int* __restrict__ cursor,
                                                  float* __restrict__ epack){
  int e = blockIdx.x * 256 + threadIdx.x;
  if (e < NE){
    int snd = ei[e], rcv = ei[NE + e];
    int key = rcv * 4 + numbers[snd];
    int p = atomicAdd(&cursor[key], 1);
    const float* C = cells + (size_t)batch[snd] * 9;
    float o0 = eoff[e*3+0], o1 = eoff[e*3+1], o2 = eoff[e*3+2];
    f32x4 rec;
    rec[0] = __int_as_float(snd);
    rec[1] = o0*C[0] + o1*C[3] + o2*C[6];
    rec[2] = o0*C[1] + o1*C[4] + o2*C[7];
    rec[3] = o0*C[2] + o1*C[5] + o2*C[8];
    *reinterpret_cast<f32x4*>(epack + (size_t)p * 4) = rec;
  }
}

__global__ __launch_bounds__(256) void k_aplace(const int* __restrict__ numbers,
                                                const int* __restrict__ boffs,
                                                int* __restrict__ list){
  __shared__ int ws[4][4];
  int tid = threadIdx.x, w = tid >> 6, lane = tid & 63;
  int i = blockIdx.x * 256 + tid;
  int sp = numbers[i];
  int rank = 0;
  #pragma unroll
  for (int s = 0; s < 4; s++){
    unsigned long long m = __ballot(sp == s);
    if (s == sp) rank = __popcll(m & (((unsigned long long)1 << lane) - 1));
    if (lane == 0) ws[w][s] = __popcll(m);
  }
  __syncthreads();
  int pre = 0;
  for (int w2 = 0; w2 < w; w2++) pre += ws[w2][sp];
  list[boffs[blockIdx.x * 4 + sp] + pre + rank] = i;
}

// ---------------- fused per-atom: packed-edge geometry -> accumulate ->
//                  U-mix -> ps (6-wave) + Gram stats ----------------------------------
__global__ __launch_bounds__(384) void k_atom(
    const float* __restrict__ pos, const float* __restrict__ epack,
    const int* __restrict__ startsK, const float* __restrict__ U,
    unsigned short* __restrict__ ps, float* __restrict__ stats)
{
  __shared__ float rf[64][7];     // r, fc, hx, hy, hz (stride 7 -> conflict-free)
  __shared__ float Rl[64][11];    // stride 11 -> conflict-free writes
  __shared__ float Yl[64][NSPH];
  __shared__ float csr[360];
  __shared__ float cl[360];
  __shared__ float ul[16];
  int atom = blockIdx.x;
  int tid = threadIdx.x;
  if (tid < 16) ul[tid] = U[tid];
  int e0 = startsK[atom * 4], e1 = startsK[atom * 4 + 4];
  float px = pos[atom*3+0], py = pos[atom*3+1], pz = pos[atom*3+2];
  int sp = tid / 90, n = (tid % 90) / 9, k = tid % 9;
  int aS = 0, aE = 0;
  if (tid < 360){ aS = startsK[atom * 4 + sp]; aE = startsK[atom * 4 + sp + 1]; }
  float acc = 0.f;
  for (int base = e0; base < e1; base += 64){
    int nch = min(64, e1 - base);
    // step 1: wave 0 computes r, fc, unit vector from packed record + pos gather
    if (tid < nch){
      f32x4 rec = *reinterpret_cast<const f32x4*>(epack + (size_t)(base + tid) * 4);
      int snd = __float_as_int(rec[0]);
      float rx = px - pos[snd*3+0] + rec[1];
      float ry = py - pos[snd*3+1] + rec[2];
      float rz = pz - pos[snd*3+2] + rec[3];
      float r = sqrtf(rx*rx + ry*ry + rz*rz + 1e-12f);
      float inv = 1.f / r;
      float fc = (r < 5.f) ? (0.5f * (__cosf(r * 0.6283185307179586f) + 1.f)) : 0.f;
      rf[tid][0] = r;
      rf[tid][1] = fc;
      rf[tid][2] = rx * inv;
      rf[tid][3] = ry * inv;
      rf[tid][4] = rz * inv;
    }
    __syncthreads();
    // step 2: component-parallel R/Y across all 6 waves
    {
      int w6 = tid >> 6, e = tid & 63;
      if (e < nch){
        if (w6 < 5){
          float r = rf[e][0], fc = rf[e][1];
          #pragma unroll
          for (int t = 0; t < 2; t++){
            int nn = w6 * 2 + t;
            float d = r - (5.f/9.f) * (float)nn;
            Rl[e][nn] = __expf(-2.f * d * d) * fc;
          }
        } else {
          float hx = rf[e][2], hy = rf[e][3], hz = rf[e][4];
          Yl[e][0] = 0.28209479177387814f;
          Yl[e][1] = 0.4886025119029199f * hy;
          Yl[e][2] = 0.4886025119029199f * hz;
          Yl[e][3] = 0.4886025119029199f * hx;
          Yl[e][4] = 1.0925484305920792f * hx * hy;
          Yl[e][5] = 1.0925484305920792f * hy * hz;
          Yl[e][6] = 0.31539156525252005f * (3.f * hz * hz - 1.f);
          Yl[e][7] = 1.0925484305920792f * hx * hz;
          Yl[e][8] = 0.5462742152960396f * (hx * hx - hy * hy);
        }
      }
    }
    __syncthreads();
    if (tid < 360){
      int lo2 = max(aS, base), hi2 = min(aE, base + nch);
      for (int e = lo2; e < hi2; e++){
        int j = e - base;
        acc += Rl[j][n] * Yl[j][k];
      }
    }
    __syncthreads();
  }
  if (tid < 360) csr[tid] = acc;
  __syncthreads();
  if (tid < 360){
    int a = tid / 90, nk = tid % 90;
    cl[tid] = ul[a*4+0]*csr[nk] + ul[a*4+1]*csr[90+nk]
            + ul[a*4+2]*csr[180+nk] + ul[a*4+3]*csr[270+nk];
  }
  __syncthreads();
  // ps: w0/w1 -> l=2 halves, w2/w3 -> l=1 halves, w4 -> l=0 full, w5 -> pad + Gram stats
  int w6 = tid >> 6, b = tid & 63;
  if (w6 <= 3 && b < 55){
    int l = (w6 < 2) ? 2 : 1;
    int qh = w6 & 1;
    int qb, pb;
    decode_blk(b, qb, pb);
    bool diag = (qb == pb);
    unsigned short ob[8];
    if (l == 2) ps_block_half<5>(cl, qb, pb, 4, 0.4472135954999579f, diag, qh, ob);
    else        ps_block_half<3>(cl, qb, pb, 1, 0.5773502691896258f, diag, qh, ob);
    unsigned short* dst = ps + (size_t)atom * FR + b * 48 + l * 16 + qh * 8;
    *reinterpret_cast<u16x8*>(dst) = *(const u16x8*)ob;
  } else if (w6 == 4 && b < 55){
    int qb, pb;
    decode_blk(b, qb, pb);
    bool diag = (qb == pb);
    unsigned short ob[16];
    ps_block<1>(cl, qb, pb, 0, 1.f, diag, ob);
    unsigned short* dst = ps + (size_t)atom * FR + b * 48;
    *reinterpret_cast<u16x8*>(dst)     = *(const u16x8*)&ob[0];
    *reinterpret_cast<u16x8*>(dst + 8) = *(const u16x8*)&ob[8];
  } else if (w6 == 5){
    if (b < 6){
      unsigned short zb[8] = {0,0,0,0,0,0,0,0};
      *reinterpret_cast<u16x8*>(ps + (size_t)atom * FR + 2640 + b * 8) = *(const u16x8*)zb;
    }
    // LN stats via closed form (Gram):
    float c1 = 0.f, c2 = 0.f;
    if (b >= 8 && b < 17){
      int kk = b - 8;
      float S = 0.f;
      for (int q = 0; q < 40; q++) S += cl[q*9 + kk];
      float nrm = (kk == 0) ? 1.f : ((kk < 4) ? 0.5773502691896258f : 0.4472135954999579f);
      c1 = nrm * S * S;
    } else if (b >= 24 && b < 46){
      int j = b - 24;
      int ka = g_ka[j], kb = g_kb[j];
      float G = 0.f;
      for (int q = 0; q < 40; q++) G += cl[q*9 + ka] * cl[q*9 + kb];
      float n2 = (ka == 0) ? 1.f : ((ka < 4) ? (1.f/3.f) : 0.2f);
      float mul = (ka == kb) ? 1.f : 2.f;
      c2 = n2 * mul * G * G;
    }
    #pragma unroll
    for (int m = 32; m; m >>= 1){ c1 += __shfl_xor(c1, m, 64); c2 += __shfl_xor(c2, m, 64); }
    if (b == 0){
      float mean = c1 * (1.f / FF);
      float var = c2 * (1.f / FF) - mean * mean;
      var = fmaxf(var, 0.f);
      stats[2*atom]   = mean;
      stats[2*atom+1] = rsqrtf(var + 1e-5f);
    }
  }
}

// ---------------- weight prep v3: SINGLE pass over W1, all 4 species at once ----------
__global__ __launch_bounds__(256) void k_wg3(
    const float* __restrict__ W1, const float* __restrict__ U,
    const float* __restrict__ gamma, const float* __restrict__ beta,
    unsigned short* __restrict__ Wg, float* __restrict__ gW, float* __restrict__ bW)
{
  __shared__ unsigned short og[4][64][64]; // [s][fi][ni], 32 KB
  int n0 = blockIdx.x * 64, f0 = blockIdx.y * 64;
  int tid = threadIdx.x, ni = tid & 63;
  float u[4][4];
  #pragma unroll
  for (int a = 0; a < 4; a++)
    #pragma unroll
    for (int s = 0; s < 4; s++) u[a][s] = U[a*4 + s];
  float gs[4] = {0,0,0,0}, bs[4] = {0,0,0,0};
  for (int rep = 0; rep < 16; rep++){
    int fi = rep * 4 + (tid >> 6);
    int fp = f0 + fi;
    int b = fp / 48, r = fp % 48;
    int l = r >> 4, qi = (r >> 2) & 3, pi = r & 3;
    float tg[4] = {0,0,0,0}, tb[4] = {0,0,0,0};
    if (b < 55){
      int qb, pb;
      decode_blk(b, qb, pb);
      bool zero = (qb == pb) && (qi > pi);
      if (!zero){
        int q = qb*4 + qi, p = pb*4 + pi;
        int fa = (q * 40 + p) * 3 + l;
        float ga = gamma[fa], ba = beta[fa];
        float wm[4] = {0,0,0,0};
        #pragma unroll
        for (int a = 0; a < 4; a++){
          float wa = W1[(size_t)a * FF * 512 + (size_t)fa * 512 + n0 + ni];
          #pragma unroll
          for (int s = 0; s < 4; s++) wm[s] += u[a][s] * wa;
        }
        #pragma unroll
        for (int s = 0; s < 4; s++){ tg[s] = ga * wm[s]; tb[s] = ba * wm[s]; }
        if (p != q){
          int fb = (p * 40 + q) * 3 + l;
          float gb = gamma[fb], bb = beta[fb];
          float wn[4] = {0,0,0,0};
          #pragma unroll
          for (int a = 0; a < 4; a++){
            float wb = W1[(size_t)a * FF * 512 + (size_t)fb * 512 + n0 + ni];
            #pragma unroll
            for (int s = 0; s < 4; s++) wn[s] += u[a][s] * wb;
          }
          #pragma unroll
          for (int s = 0; s < 4; s++){ tg[s] += gb * wn[s]; tb[s] += bb * wn[s]; }
        }
      }
    }
    #pragma unroll
    for (int s = 0; s < 4; s++){
      og[s][fi][ni] = f2bf(tg[s]);
      gs[s] += tg[s];
      bs[s] += tb[s];
    }
  }
  #pragma unroll
  for (int s = 0; s < 4; s++){
    atomic_add_f(&gW[s * 512 + n0 + ni], gs[s]);
    atomic_add_f(&bW[s * 512 + n0 + ni], bs[s]);
  }
  __syncthreads();
  for (int it = 0; it < 8; it++){
    int idx = it * 256 + tid;      // 2048 u16x8 chunks: [s][nn][c]
    int c = idx & 7;
    int rrow = idx >> 3;
    int s = rrow >> 6, nn = rrow & 63;
    unsigned short o[8];
    #pragma unroll
    for (int j = 0; j < 8; j++) o[j] = og[s][c*8 + j][nn];
    *reinterpret_cast<u16x8*>(&Wg[((size_t)s * 512 + n0 + nn) * FR + f0 + c * 8]) = *(const u16x8*)o;
  }
}

// W2 mix (+ W3s slice computed by the x==0,y==0 block of each species)
__global__ __launch_bounds__(256) void k_w2t(
    const float* __restrict__ W2, const float* __restrict__ U,
    unsigned short* __restrict__ W2t,
    const float* __restrict__ W3, float* __restrict__ W3s)
{
  __shared__ float t[64][65];
  int n0 = blockIdx.x * 64, k0 = blockIdx.y * 64, s = blockIdx.z;
  float u0 = U[s], u1 = U[4+s], u2 = U[8+s], u3 = U[12+s];
  int tid = threadIdx.x;
  if (blockIdx.x == 0 && blockIdx.y == 0){
    for (int k = tid; k < 512; k += 256)
      W3s[s*512 + k] = u0*W3[k] + u1*W3[512+k] + u2*W3[2*512+k] + u3*W3[3*512+k];
  }
  #pragma unroll 4
  for (int rep = 0; rep < 16; rep++){
    int idx = rep * 256 + tid;
    int ki = idx >> 6, ni = idx & 63;
    size_t base = (size_t)(k0 + ki) * 512 + (n0 + ni);
    t[ki][ni] = u0*W2[base] + u1*W2[base + 512*512]
              + u2*W2[base + 2*512*512] + u3*W2[base + 3*512*512];
  }
  __syncthreads();
  #pragma unroll 4
  for (int rep = 0; rep < 16; rep++){
    int idx = rep * 256 + tid;
    int ni = idx >> 6, ki = idx & 63;
    W2t[((size_t)s * 512 + n0 + ni) * 512 + k0 + ki] = f2bf(t[ki][ni]);
  }
}

// ---------------- GEMM template (128x128 tile, BK=64, bf16 MFMA) ----------------
template<int EPI, int NSPLIT>
__global__ __launch_bounds__(256) void k_gemm(
    const unsigned short* __restrict__ Ag, int lda, int K,
    const unsigned short* __restrict__ Btg,
    const int* __restrict__ list, const int* __restrict__ offs, const int* __restrict__ cnt,
    unsigned short* __restrict__ pout,
    const float* __restrict__ W3s, float* __restrict__ pacc)
{
  __shared__ alignas(16) char smem[32768];
  const int NV = 4 * NSPLIT;
  int b = blockIdx.x;
  int y = (b & 7) + 8 * (b / (8 * NV));
  int v = (b >> 3) % NV;
  int x = v & 3, kh = v >> 2;

  int s = 0, t = y;
  for (; s < 4; s++){
    int nts = (cnt[s] + 127) >> 7;
    if (t < nts) break;
    t -= nts;
  }
  if (s >= 4) return;
  int cntS = cnt[s], offS = offs[s];
  int rt = t, n0 = x * 128;
  int tid = threadIdx.x, w = tid >> 6, lane = tid & 63;
  int wr = w >> 1, wc = w & 1;

  const unsigned short* Bts = Btg + (size_t)s * 512 * K;
  const unsigned short* gA[4];
  const unsigned short* gB[4];
  char* lA[4];
  char* lB[4];
  #pragma unroll
  for (int it = 0; it < 4; it++){
    int g = it * 4 + w;
    int idx = g * 64 + lane;
    int row = idx >> 3, ch = idx & 7;
    int cg = ch ^ (row & 7);
    int gr = rt * 128 + row; gr = gr < cntS ? gr : cntS - 1;
    int atom = list[offS + gr];
    gA[it] = Ag + (size_t)atom * lda + cg * 8;
    lA[it] = smem + g * 1024;
    gB[it] = Bts + (size_t)(n0 + row) * K + cg * 8;
    lB[it] = smem + 16384 + g * 1024;
  }

  int hi = lane >> 4, lo = lane & 15;
  f32x4 acc[4][4];
  #pragma unroll
  for (int mi = 0; mi < 4; mi++)
    #pragma unroll
    for (int ni = 0; ni < 4; ni++)
      #pragma unroll
      for (int r = 0; r < 4; r++) acc[mi][ni][r] = 0.f;

  int abase[4], a7[4], bbase[4], b7[4];
  #pragma unroll
  for (int mi = 0; mi < 4; mi++){ int row = wr*64 + mi*16 + lo; abase[mi] = row*128; a7[mi] = row & 7; }
  #pragma unroll
  for (int ni = 0; ni < 4; ni++){ int row = wc*64 + ni*16 + lo; bbase[ni] = 16384 + row*128; b7[ni] = row & 7; }

  int nk = K / 64;
  int k0 = ((nk * kh) / NSPLIT) * 64;
  int k1 = ((nk * (kh + 1)) / NSPLIT) * 64;

  for (int kt = k0; kt < k1; kt += 64){
    #pragma unroll
    for (int it = 0; it < 4; it++) gload16(gA[it] + kt, lA[it]);
    #pragma unroll
    for (int it = 0; it < 4; it++) gload16(gB[it] + kt, lB[it]);
    __syncthreads();
    #pragma unroll
    for (int kk = 0; kk < 2; kk++){
      bf16x8 af[4], bfr[4];
      #pragma unroll
      for (int mi = 0; mi < 4; mi++)
        af[mi] = *(const bf16x8*)(smem + abase[mi] + (((kk*4 + hi) ^ a7[mi]) << 4));
      #pragma unroll
      for (int ni = 0; ni < 4; ni++)
        bfr[ni] = *(const bf16x8*)(smem + bbase[ni] + (((kk*4 + hi) ^ b7[ni]) << 4));
      #pragma unroll
      for (int mi = 0; mi < 4; mi++)
        #pragma unroll
        for (int ni = 0; ni < 4; ni++)
          acc[mi][ni] = __builtin_amdgcn_mfma_f32_16x16x32_bf16(af[mi], bfr[ni], acc[mi][ni], 0, 0, 0);
    }
    __syncthreads();
  }

  int gn[4];
  #pragma unroll
  for (int ni = 0; ni < 4; ni++) gn[ni] = n0 + wc*64 + ni*16 + lo;

  if (EPI == 0){
    #pragma unroll
    for (int mi = 0; mi < 4; mi++){
      #pragma unroll
      for (int j = 0; j < 4; j++){
        int gr = rt*128 + wr*64 + mi*16 + hi*4 + j;
        if (gr < cntS){
          int atom = list[offS + gr];
          #pragma unroll
          for (int ni = 0; ni < 4; ni++)
            pout[((size_t)kh * NA + atom) * 512 + gn[ni]] = f2bf(acc[mi][ni][j]);
        }
      }
    }
  } else {
    float w3v[4];
    #pragma unroll
    for (int ni = 0; ni < 4; ni++) w3v[ni] = W3s[s * 512 + gn[ni]];
    float* pslot = pacc + (size_t)(x * 2 + wc) * NA;
    #pragma unroll
    for (int mi = 0; mi < 4; mi++){
      #pragma unroll
      for (int j = 0; j < 4; j++){
        int gr = rt*128 + wr*64 + mi*16 + hi*4 + j;
        if (gr < cntS){
          int atom = list[offS + gr];
          float pdot = 0.f;
          #pragma unroll
          for (int ni = 0; ni < 4; ni++)
            pdot += silu(acc[mi][ni][j]) * w3v[ni];
          pdot += __shfl_xor(pdot, 1, 16);
          pdot += __shfl_xor(pdot, 2, 16);
          pdot += __shfl_xor(pdot, 4, 16);
          pdot += __shfl_xor(pdot, 8, 16);
          if (lo == 0) pslot[atom] = pdot;
        }
      }
    }
  }
}

// ---------------- epilogue: combine 4 split-K partials + LN-affine + silu -> h1 -------
__global__ __launch_bounds__(256) void k_epi(
    const unsigned short* __restrict__ pbuf, const float* __restrict__ stats,
    const float* __restrict__ gW, const float* __restrict__ bW,
    const int* __restrict__ numbers, unsigned short* __restrict__ h1)
{
  int w = threadIdx.x >> 6, lane = threadIdx.x & 63;
  int atom = blockIdx.x * 4 + w;
  int s = numbers[atom];
  float mean = stats[2*atom], rstd = stats[2*atom+1];
  int c0 = lane * 8;
  u16x8 a0 = *reinterpret_cast<const u16x8*>(pbuf + (size_t)atom * 512 + c0);
  u16x8 a1 = *reinterpret_cast<const u16x8*>(pbuf + (size_t)(NA + atom) * 512 + c0);
  u16x8 a2 = *reinterpret_cast<const u16x8*>(pbuf + (size_t)(2*NA + atom) * 512 + c0);
  u16x8 a3 = *reinterpret_cast<const u16x8*>(pbuf + (size_t)(3*NA + atom) * 512 + c0);
  unsigned short o[8];
  #pragma unroll
  for (int j = 0; j < 8; j++){
    int c = c0 + j;
    float acc = (bf2f(a0[j]) + bf2f(a1[j])) + (bf2f(a2[j]) + bf2f(a3[j]));
    float vv = rstd * acc + bW[s*512 + c] - mean * rstd * gW[s*512 + c];
    o[j] = f2bf(silu(vv));
  }
  *reinterpret_cast<u16x8*>(h1 + (size_t)atom * 512 + c0) = *(const u16x8*)o;
}

// ---------------- final: sum 8 pacc partials/atom, wave-uniform molecule atomic -------
__global__ __launch_bounds__(256) void k_final2(
    const float* __restrict__ pacc, const int* __restrict__ numbers,
    const int* __restrict__ batch, const float* __restrict__ Wc,
    float* __restrict__ molOut)
{
  int atom = blockIdx.x * 256 + threadIdx.x;
  int lane = threadIdx.x & 63;
  float sum = 0.f;
  #pragma unroll
  for (int p = 0; p < 8; p++) sum += pacc[(size_t)p * NA + atom];
  float val = sum * (1.f / 128.f) + Wc[numbers[atom]];
  int mol = batch[atom];
  int m0 = __shfl(mol, 0, 64);
  int m63 = __shfl(mol, 63, 64);
  if (m0 == m63){
    #pragma unroll
    for (int m = 32; m; m >>= 1) val += __shfl_xor(val, m, 64);
    if (lane == 0) atomic_add_f(&molOut[mol], val);
  } else {
    atomic_add_f(&molOut[mol], val);
  }
}

extern "C" void kernel_launch(void* const* d_in, const int* in_sizes, int n_in,
                              void* d_out, int out_size, void* d_ws, size_t ws_size,
                              hipStream_t stream)
{
  const float* pos     = (const float*)d_in[0];
  const float* cells   = (const float*)d_in[1];
  const int*   numbers = (const int*)d_in[2];
  const int*   ei      = (const int*)d_in[3];
  const float* eoff    = (const float*)d_in[4];
  const int*   batch   = (const int*)d_in[5];
  const float* U       = (const float*)d_in[6];
  const float* gamma   = (const float*)d_in[7];
  const float* beta    = (const float*)d_in[8];
  const float* W1      = (const float*)d_in[9];
  const float* W2      = (const float*)d_in[10];
  const float* W3      = (const float*)d_in[11];
  const float* Wc      = (const float*)d_in[12];
  float* out = (float*)d_out;

  char* ws = (char*)d_ws;
  size_t off = 0;
  auto alloc = [&](size_t bytes) -> void* {
    void* p = ws + off;
    off += (bytes + 255) & ~(size_t)255;
    return p;
  };
  unsigned short* ps   = (unsigned short*)alloc((size_t)NA * FR * 2);      // 88 MB
  unsigned short* pbuf = (unsigned short*)alloc((size_t)4 * NA * 512 * 2); // 64 MB
  float* stats         = (float*)alloc((size_t)NA * 2 * 4);
  unsigned short* Wg1  = (unsigned short*)alloc((size_t)4 * 512 * FR * 2); // 11 MB
  unsigned short* W2t  = (unsigned short*)alloc((size_t)4 * 512 * 512 * 2);
  float* W3s           = (float*)alloc(4 * 512 * 4);
  unsigned short* h1   = (unsigned short*)alloc((size_t)NA * 512 * 2);
  float* pacc          = (float*)alloc((size_t)8 * NA * 4);
  int* list            = (int*)alloc(NA * 4);
  float* epack         = (float*)alloc((size_t)NE * 4 * 4);                // 8 MB
  int* startsK         = (int*)alloc((65536 + 1) * 4);
  // contiguous zero-init region: cnt64k + gW + bW (one memset)
  int* cnt64k          = (int*)alloc(65536 * 4);
  float* gW            = (float*)alloc(4 * 512 * 4);
  float* bW            = (float*)alloc(4 * 512 * 4);
  int* cursor64k       = (int*)alloc(65536 * 4);
  int* bsum            = (int*)alloc(256 * 4);
  int* boff            = (int*)alloc(256 * 4);
  int* bhist           = (int*)alloc(64 * 4 * 4);
  int* boffs           = (int*)alloc(64 * 4 * 4);
  int* ints            = (int*)alloc(64);
  int* cnt = ints; int* offs = ints + 8;

  hipMemsetAsync(cnt64k, 0, 65536 * 4 + 2 * 4 * 512 * 4, stream);
  hipMemsetAsync(out, 0, (size_t)out_size * 4, stream);

  // edge hist (by recv*4+species) + atom hist, fused
  k_hist<<<2048 + 64, 256, 0, stream>>>(ei, numbers, cnt64k, bhist);
  k_scanA<<<256, 256, 0, stream>>>(cnt64k, bsum);
  k_scanB<<<1, 256, 0, stream>>>(bsum, boff, startsK, bhist, boffs, ints);
  k_scanC<<<256, 256, 0, stream>>>(cnt64k, boff, startsK, cursor64k);
  k_sortpack<<<NE / 256, 256, 0, stream>>>(ei, numbers, eoff, cells, batch,
                                           cursor64k, epack);
  k_aplace<<<NA / 256, 256, 0, stream>>>(numbers, boffs, list);

  // fused per-atom pipeline (packed-edge geometry, 6-wave ps, Gram stats)
  k_atom<<<NA, 384, 0, stream>>>(pos, epack, startsK, U, ps, stats);

  // weight prep (single pass over W1; W2 mix + W3 mix fused)
  k_wg3<<<dim3(8, 42), 256, 0, stream>>>(W1, U, gamma, beta, Wg1, gW, bW);
  k_w2t<<<dim3(8, 8, 4), 256, 0, stream>>>(W2, U, W2t, W3, W3s);

  // GEMM1 split-K=4 (K=2688, 2176 blocks), then LN+silu epilogue
  k_gemm<0, 4><<<2176, 256, 0, stream>>>(ps, FR, FR, Wg1, list, offs, cnt,
                                         pbuf, nullptr, nullptr);
  k_epi<<<NA / 4, 256, 0, stream>>>(pbuf, stats, gW, bW, numbers, h1);

  // GEMM2 with fused silu + W3 dot -> per-atom partials (atomic-free)
  k_gemm<2, 1><<<544, 256, 0, stream>>>(h1, 512, 512, W2t, list, offs, cnt,
                                        nullptr, W3s, pacc);
  k_final2<<<NA / 256, 256, 0, stream>>>(pacc, numbers, batch, Wc, out);
}

// Round 21
// 292.531 us; speedup vs baseline: 1.1100x; 1.0415x over previous
//
#include <hip/hip_runtime.h>

#define NA   16384
#define NE   524288
#define NM   256
#define FF   4800
#define FR   2688   // folded K: 55 pair-blocks * 48 + 48 pad ; f' = b*48 + l*16 + qi*4 + pi
#define HH   512
#define NMX  10
#define NSPH 9

typedef __bf16 bf16x8 __attribute__((ext_vector_type(8)));
typedef float  f32x4  __attribute__((ext_vector_type(4)));
typedef unsigned short u16x8 __attribute__((ext_vector_type(8)));

__constant__ int g_ka[22] = {0, 1,1,1,2,2,3, 4,4,4,4,4, 5,5,5,5, 6,6,6, 7,7, 8};
__constant__ int g_kb[22] = {0, 1,2,3,2,3,3, 4,5,6,7,8, 5,6,7,8, 6,7,8, 7,8, 8};

__device__ inline unsigned short f2bf(float x){
  return __builtin_bit_cast(unsigned short, (__bf16)x);
}
__device__ inline float bf2f(unsigned short h){
  unsigned int u = ((unsigned int)h) << 16;
  return __builtin_bit_cast(float, u);
}
__device__ inline void atomic_add_f(float* p, float v){
  __hip_atomic_fetch_add(p, v, __ATOMIC_RELAXED, __HIP_MEMORY_SCOPE_AGENT);
}
__device__ inline void gload16(const void* g, void* l){
  __builtin_amdgcn_global_load_lds(
      (const __attribute__((address_space(1))) unsigned int*)g,
      (__attribute__((address_space(3))) unsigned int*)l, 16, 0, 0);
}
__device__ inline float silu(float x){ return x / (1.f + __expf(-x)); }

// decode pair-block b (0..54) -> (qb, pb), qb <= pb < 10
__device__ inline void decode_blk(int b, int& qb, int& pb){
  int q = 0, rem = b;
  while (rem >= 10 - q){ rem -= 10 - q; q++; }
  qb = q; pb = q + rem;
}

// full 4x4 pair block for one l (CNT components), outputs only
template<int CNT>
__device__ inline void ps_block(const float* __restrict__ cl, int qb, int pb, int off,
                                float nrm, bool diag, unsigned short* ob){
  float cq[4][CNT], cp[4][CNT];
  #pragma unroll
  for (int i = 0; i < 4; i++)
    #pragma unroll
    for (int k = 0; k < CNT; k++){
      cq[i][k] = cl[(qb*4 + i)*9 + off + k];
      cp[i][k] = cl[(pb*4 + i)*9 + off + k];
    }
  #pragma unroll
  for (int qi = 0; qi < 4; qi++)
    #pragma unroll
    for (int pi = 0; pi < 4; pi++){
      float v = 0.f;
      #pragma unroll
      for (int k = 0; k < CNT; k++) v += cq[qi][k] * cp[pi][k];
      v *= nrm;
      if (diag && qi > pi) v = 0.f;
      ob[qi*4 + pi] = f2bf(v);
    }
}

// half (2 qi rows x 4 pi) of a 4x4 pair block: 8 outputs, outputs only
template<int CNT>
__device__ inline void ps_block_half(const float* __restrict__ cl, int qb, int pb, int off,
                                     float nrm, bool diag, int qh, unsigned short* ob){
  float cq[2][CNT], cp[4][CNT];
  #pragma unroll
  for (int i = 0; i < 2; i++)
    #pragma unroll
    for (int k = 0; k < CNT; k++)
      cq[i][k] = cl[(qb*4 + qh*2 + i)*9 + off + k];
  #pragma unroll
  for (int i = 0; i < 4; i++)
    #pragma unroll
    for (int k = 0; k < CNT; k++)
      cp[i][k] = cl[(pb*4 + i)*9 + off + k];
  #pragma unroll
  for (int qi = 0; qi < 2; qi++)
    #pragma unroll
    for (int pi = 0; pi < 4; pi++){
      int qg = qh*2 + qi;
      float v = 0.f;
      #pragma unroll
      for (int k = 0; k < CNT; k++) v += cq[qi][k] * cp[pi][k];
      v *= nrm;
      if (diag && qg > pi) v = 0.f;
      ob[qi*4 + pi] = f2bf(v);
    }
}

__device__ inline int block_scan_excl(int v, int tid, int* lds){
  int lane = tid & 63, w = tid >> 6;
  int x = v;
  #pragma unroll
  for (int d = 1; d < 64; d <<= 1){
    int y = __shfl_up(x, d, 64);
    if (lane >= d) x += y;
  }
  if (lane == 63) lds[w] = x;
  __syncthreads();
  int wsum = 0;
  for (int i = 0; i < w; i++) wsum += lds[i];
  return wsum + x - v;
}

// ---------------- edge hist (2048 blocks) + atom hist (64 blocks), fused --------------
__global__ __launch_bounds__(256) void k_hist(const int* __restrict__ ei,
                                              const int* __restrict__ numbers,
                                              int* __restrict__ cnt64k,
                                              int* __restrict__ bhist){
  __shared__ int h[4];
  int blk = blockIdx.x, tid = threadIdx.x;
  if (blk < 2048){
    int e = blk * 256 + tid;
    int key = ei[NE + e] * 4 + numbers[ei[e]];
    atomicAdd(&cnt64k[key], 1);
  } else {
    if (tid < 4) h[tid] = 0;
    __syncthreads();
    atomicAdd(&h[numbers[(blk - 2048) * 256 + tid]], 1);
    __syncthreads();
    if (tid < 4) bhist[(blk - 2048) * 4 + tid] = h[tid];
  }
}

__global__ __launch_bounds__(256) void k_scanA(const int* __restrict__ cnt64k,
                                               int* __restrict__ bsum){
  __shared__ int lds[4];
  int tid = threadIdx.x;
  int v = cnt64k[blockIdx.x * 256 + tid];
  int lane = tid & 63;
  #pragma unroll
  for (int m = 32; m; m >>= 1) v += __shfl_xor(v, m, 64);
  if (lane == 0) lds[tid >> 6] = v;
  __syncthreads();
  if (tid == 0) bsum[blockIdx.x] = lds[0] + lds[1] + lds[2] + lds[3];
}

// scan of 256 block sums + atom-species offsets (fused serial tail)
__global__ __launch_bounds__(256) void k_scanB(const int* __restrict__ bsum,
                                               int* __restrict__ boff, int* __restrict__ starts,
                                               const int* __restrict__ bhist,
                                               int* __restrict__ boffs, int* __restrict__ ints){
  __shared__ int lds[4];
  int tid = threadIdx.x;
  int v = bsum[tid];
  int e = block_scan_excl(v, tid, lds);
  boff[tid] = e;
  if (tid == 0){
    starts[65536] = NE;
    int* cnt = ints; int* offs = ints + 8;
    int tot[4] = {0,0,0,0};
    for (int b = 0; b < 64; b++)
      for (int s = 0; s < 4; s++) tot[s] += bhist[b*4 + s];
    int o = 0;
    for (int s = 0; s < 4; s++){ cnt[s] = tot[s]; offs[s] = o; o += tot[s]; }
    offs[4] = o;
    int run[4];
    for (int s = 0; s < 4; s++) run[s] = offs[s];
    for (int b = 0; b < 64; b++)
      for (int s = 0; s < 4; s++){ boffs[b*4 + s] = run[s]; run[s] += bhist[b*4 + s]; }
  }
}

__global__ __launch_bounds__(256) void k_scanC(const int* __restrict__ cnt64k,
                                               const int* __restrict__ boff,
                                               int* __restrict__ starts, int* __restrict__ cursor){
  __shared__ int lds[4];
  int tid = threadIdx.x;
  int bin = blockIdx.x * 256 + tid;
  int v = cnt64k[bin];
  int e = block_scan_excl(v, tid, lds) + boff[blockIdx.x];
  starts[bin] = e;
  cursor[bin] = e;
}

// sort + pack FULL rvec: epack[p] = {rvx, rvy, rvz, 0} -> k_atom has ZERO gathers
__global__ __launch_bounds__(256) void k_sortpack(const int* __restrict__ ei,
                                                  const int* __restrict__ numbers,
                                                  const float* __restrict__ eoff,
                                                  const float* __restrict__ cells,
                                                  const int* __restrict__ batch,
                                                  const float* __restrict__ pos,
                                                  int* __restrict__ cursor,
                                                  float* __restrict__ epack){
  int e = blockIdx.x * 256 + threadIdx.x;
  if (e < NE){
    int snd = ei[e], rcv = ei[NE + e];
    int key = rcv * 4 + numbers[snd];
    int p = atomicAdd(&cursor[key], 1);
    const float* C = cells + (size_t)batch[snd] * 9;
    float o0 = eoff[e*3+0], o1 = eoff[e*3+1], o2 = eoff[e*3+2];
    f32x4 rec;
    rec[0] = pos[rcv*3+0] - pos[snd*3+0] + o0*C[0] + o1*C[3] + o2*C[6];
    rec[1] = pos[rcv*3+1] - pos[snd*3+1] + o0*C[1] + o1*C[4] + o2*C[7];
    rec[2] = pos[rcv*3+2] - pos[snd*3+2] + o0*C[2] + o1*C[5] + o2*C[8];
    rec[3] = 0.f;
    *reinterpret_cast<f32x4*>(epack + (size_t)p * 4) = rec;
  }
}

__global__ __launch_bounds__(256) void k_aplace(const int* __restrict__ numbers,
                                                const int* __restrict__ boffs,
                                                int* __restrict__ list){
  __shared__ int ws[4][4];
  int tid = threadIdx.x, w = tid >> 6, lane = tid & 63;
  int i = blockIdx.x * 256 + tid;
  int sp = numbers[i];
  int rank = 0;
  #pragma unroll
  for (int s = 0; s < 4; s++){
    unsigned long long m = __ballot(sp == s);
    if (s == sp) rank = __popcll(m & (((unsigned long long)1 << lane) - 1));
    if (lane == 0) ws[w][s] = __popcll(m);
  }
  __syncthreads();
  int pre = 0;
  for (int w2 = 0; w2 < w; w2++) pre += ws[w2][sp];
  list[boffs[blockIdx.x * 4 + sp] + pre + rank] = i;
}

// ---------------- fused per-atom: streaming rvec -> accumulate -> U-mix ->
//                  ps (6-wave) + Gram stats -------------------------------------------
__global__ __launch_bounds__(384) void k_atom(
    const float* __restrict__ epack, const int* __restrict__ startsK,
    const float* __restrict__ U,
    unsigned short* __restrict__ ps, float* __restrict__ stats)
{
  __shared__ float rf[64][7];     // r, fc, hx, hy, hz (stride 7 -> conflict-free)
  __shared__ float Rl[64][11];    // stride 11 -> conflict-free writes
  __shared__ float Yl[64][NSPH];
  __shared__ float csr[360];
  __shared__ float cl[360];
  __shared__ float ul[16];
  int atom = blockIdx.x;
  int tid = threadIdx.x;
  if (tid < 16) ul[tid] = U[tid];
  int e0 = startsK[atom * 4], e1 = startsK[atom * 4 + 4];
  int sp = tid / 90, n = (tid % 90) / 9, k = tid % 9;
  int aS = 0, aE = 0;
  if (tid < 360){ aS = startsK[atom * 4 + sp]; aE = startsK[atom * 4 + sp + 1]; }
  float acc = 0.f;
  for (int base = e0; base < e1; base += 64){
    int nch = min(64, e1 - base);
    // step 1: wave 0 computes r, fc, unit vector from packed rvec (no gathers)
    if (tid < nch){
      f32x4 rec = *reinterpret_cast<const f32x4*>(epack + (size_t)(base + tid) * 4);
      float rx = rec[0], ry = rec[1], rz = rec[2];
      float r = sqrtf(rx*rx + ry*ry + rz*rz + 1e-12f);
      float inv = 1.f / r;
      float fc = (r < 5.f) ? (0.5f * (__cosf(r * 0.6283185307179586f) + 1.f)) : 0.f;
      rf[tid][0] = r;
      rf[tid][1] = fc;
      rf[tid][2] = rx * inv;
      rf[tid][3] = ry * inv;
      rf[tid][4] = rz * inv;
    }
    __syncthreads();
    // step 2: component-parallel R/Y across all 6 waves
    {
      int w6 = tid >> 6, e = tid & 63;
      if (e < nch){
        if (w6 < 5){
          float r = rf[e][0], fc = rf[e][1];
          #pragma unroll
          for (int t = 0; t < 2; t++){
            int nn = w6 * 2 + t;
            float d = r - (5.f/9.f) * (float)nn;
            Rl[e][nn] = __expf(-2.f * d * d) * fc;
          }
        } else {
          float hx = rf[e][2], hy = rf[e][3], hz = rf[e][4];
          Yl[e][0] = 0.28209479177387814f;
          Yl[e][1] = 0.4886025119029199f * hy;
          Yl[e][2] = 0.4886025119029199f * hz;
          Yl[e][3] = 0.4886025119029199f * hx;
          Yl[e][4] = 1.0925484305920792f * hx * hy;
          Yl[e][5] = 1.0925484305920792f * hy * hz;
          Yl[e][6] = 0.31539156525252005f * (3.f * hz * hz - 1.f);
          Yl[e][7] = 1.0925484305920792f * hx * hz;
          Yl[e][8] = 0.5462742152960396f * (hx * hx - hy * hy);
        }
      }
    }
    __syncthreads();
    if (tid < 360){
      int lo2 = max(aS, base), hi2 = min(aE, base + nch);
      for (int e = lo2; e < hi2; e++){
        int j = e - base;
        acc += Rl[j][n] * Yl[j][k];
      }
    }
    __syncthreads();
  }
  if (tid < 360) csr[tid] = acc;
  __syncthreads();
  if (tid < 360){
    int a = tid / 90, nk = tid % 90;
    cl[tid] = ul[a*4+0]*csr[nk] + ul[a*4+1]*csr[90+nk]
            + ul[a*4+2]*csr[180+nk] + ul[a*4+3]*csr[270+nk];
  }
  __syncthreads();
  // ps: w0/w1 -> l=2 halves, w2/w3 -> l=1 halves, w4 -> l=0 full, w5 -> pad + Gram stats
  int w6 = tid >> 6, b = tid & 63;
  if (w6 <= 3 && b < 55){
    int l = (w6 < 2) ? 2 : 1;
    int qh = w6 & 1;
    int qb, pb;
    decode_blk(b, qb, pb);
    bool diag = (qb == pb);
    unsigned short ob[8];
    if (l == 2) ps_block_half<5>(cl, qb, pb, 4, 0.4472135954999579f, diag, qh, ob);
    else        ps_block_half<3>(cl, qb, pb, 1, 0.5773502691896258f, diag, qh, ob);
    unsigned short* dst = ps + (size_t)atom * FR + b * 48 + l * 16 + qh * 8;
    *reinterpret_cast<u16x8*>(dst) = *(const u16x8*)ob;
  } else if (w6 == 4 && b < 55){
    int qb, pb;
    decode_blk(b, qb, pb);
    bool diag = (qb == pb);
    unsigned short ob[16];
    ps_block<1>(cl, qb, pb, 0, 1.f, diag, ob);
    unsigned short* dst = ps + (size_t)atom * FR + b * 48;
    *reinterpret_cast<u16x8*>(dst)     = *(const u16x8*)&ob[0];
    *reinterpret_cast<u16x8*>(dst + 8) = *(const u16x8*)&ob[8];
  } else if (w6 == 5){
    if (b < 6){
      unsigned short zb[8] = {0,0,0,0,0,0,0,0};
      *reinterpret_cast<u16x8*>(ps + (size_t)atom * FR + 2640 + b * 8) = *(const u16x8*)zb;
    }
    // LN stats via closed form (Gram):
    float c1 = 0.f, c2 = 0.f;
    if (b >= 8 && b < 17){
      int kk = b - 8;
      float S = 0.f;
      for (int q = 0; q < 40; q++) S += cl[q*9 + kk];
      float nrm = (kk == 0) ? 1.f : ((kk < 4) ? 0.5773502691896258f : 0.4472135954999579f);
      c1 = nrm * S * S;
    } else if (b >= 24 && b < 46){
      int j = b - 24;
      int ka = g_ka[j], kb = g_kb[j];
      float G = 0.f;
      for (int q = 0; q < 40; q++) G += cl[q*9 + ka] * cl[q*9 + kb];
      float n2 = (ka == 0) ? 1.f : ((ka < 4) ? (1.f/3.f) : 0.2f);
      float mul = (ka == kb) ? 1.f : 2.f;
      c2 = n2 * mul * G * G;
    }
    #pragma unroll
    for (int m = 32; m; m >>= 1){ c1 += __shfl_xor(c1, m, 64); c2 += __shfl_xor(c2, m, 64); }
    if (b == 0){
      float mean = c1 * (1.f / FF);
      float var = c2 * (1.f / FF) - mean * mean;
      var = fmaxf(var, 0.f);
      stats[2*atom]   = mean;
      stats[2*atom+1] = rsqrtf(var + 1e-5f);
    }
  }
}

// ---------------- weight prep v3: SINGLE pass over W1, all 4 species at once ----------
__global__ __launch_bounds__(256) void k_wg3(
    const float* __restrict__ W1, const float* __restrict__ U,
    const float* __restrict__ gamma, const float* __restrict__ beta,
    unsigned short* __restrict__ Wg, float* __restrict__ gW, float* __restrict__ bW)
{
  __shared__ unsigned short og[4][64][64]; // [s][fi][ni], 32 KB
  int n0 = blockIdx.x * 64, f0 = blockIdx.y * 64;
  int tid = threadIdx.x, ni = tid & 63;
  float u[4][4];
  #pragma unroll
  for (int a = 0; a < 4; a++)
    #pragma unroll
    for (int s = 0; s < 4; s++) u[a][s] = U[a*4 + s];
  float gs[4] = {0,0,0,0}, bs[4] = {0,0,0,0};
  for (int rep = 0; rep < 16; rep++){
    int fi = rep * 4 + (tid >> 6);
    int fp = f0 + fi;
    int b = fp / 48, r = fp % 48;
    int l = r >> 4, qi = (r >> 2) & 3, pi = r & 3;
    float tg[4] = {0,0,0,0}, tb[4] = {0,0,0,0};
    if (b < 55){
      int qb, pb;
      decode_blk(b, qb, pb);
      bool zero = (qb == pb) && (qi > pi);
      if (!zero){
        int q = qb*4 + qi, p = pb*4 + pi;
        int fa = (q * 40 + p) * 3 + l;
        float ga = gamma[fa], ba = beta[fa];
        float wm[4] = {0,0,0,0};
        #pragma unroll
        for (int a = 0; a < 4; a++){
          float wa = W1[(size_t)a * FF * 512 + (size_t)fa * 512 + n0 + ni];
          #pragma unroll
          for (int s = 0; s < 4; s++) wm[s] += u[a][s] * wa;
        }
        #pragma unroll
        for (int s = 0; s < 4; s++){ tg[s] = ga * wm[s]; tb[s] = ba * wm[s]; }
        if (p != q){
          int fb = (p * 40 + q) * 3 + l;
          float gb = gamma[fb], bb = beta[fb];
          float wn[4] = {0,0,0,0};
          #pragma unroll
          for (int a = 0; a < 4; a++){
            float wb = W1[(size_t)a * FF * 512 + (size_t)fb * 512 + n0 + ni];
            #pragma unroll
            for (int s = 0; s < 4; s++) wn[s] += u[a][s] * wb;
          }
          #pragma unroll
          for (int s = 0; s < 4; s++){ tg[s] += gb * wn[s]; tb[s] += bb * wn[s]; }
        }
      }
    }
    #pragma unroll
    for (int s = 0; s < 4; s++){
      og[s][fi][ni] = f2bf(tg[s]);
      gs[s] += tg[s];
      bs[s] += tb[s];
    }
  }
  #pragma unroll
  for (int s = 0; s < 4; s++){
    atomic_add_f(&gW[s * 512 + n0 + ni], gs[s]);
    atomic_add_f(&bW[s * 512 + n0 + ni], bs[s]);
  }
  __syncthreads();
  for (int it = 0; it < 8; it++){
    int idx = it * 256 + tid;      // 2048 u16x8 chunks: [s][nn][c]
    int c = idx & 7;
    int rrow = idx >> 3;
    int s = rrow >> 6, nn = rrow & 63;
    unsigned short o[8];
    #pragma unroll
    for (int j = 0; j < 8; j++) o[j] = og[s][c*8 + j][nn];
    *reinterpret_cast<u16x8*>(&Wg[((size_t)s * 512 + n0 + nn) * FR + f0 + c * 8]) = *(const u16x8*)o;
  }
}

// W2 mix (+ W3s slice computed by the x==0,y==0 block of each species)
__global__ __launch_bounds__(256) void k_w2t(
    const float* __restrict__ W2, const float* __restrict__ U,
    unsigned short* __restrict__ W2t,
    const float* __restrict__ W3, float* __restrict__ W3s)
{
  __shared__ float t[64][65];
  int n0 = blockIdx.x * 64, k0 = blockIdx.y * 64, s = blockIdx.z;
  float u0 = U[s], u1 = U[4+s], u2 = U[8+s], u3 = U[12+s];
  int tid = threadIdx.x;
  if (blockIdx.x == 0 && blockIdx.y == 0){
    for (int k = tid; k < 512; k += 256)
      W3s[s*512 + k] = u0*W3[k] + u1*W3[512+k] + u2*W3[2*512+k] + u3*W3[3*512+k];
  }
  #pragma unroll 4
  for (int rep = 0; rep < 16; rep++){
    int idx = rep * 256 + tid;
    int ki = idx >> 6, ni = idx & 63;
    size_t base = (size_t)(k0 + ki) * 512 + (n0 + ni);
    t[ki][ni] = u0*W2[base] + u1*W2[base + 512*512]
              + u2*W2[base + 2*512*512] + u3*W2[base + 3*512*512];
  }
  __syncthreads();
  #pragma unroll 4
  for (int rep = 0; rep < 16; rep++){
    int idx = rep * 256 + tid;
    int ni = idx >> 6, ki = idx & 63;
    W2t[((size_t)s * 512 + n0 + ni) * 512 + k0 + ki] = f2bf(t[ki][ni]);
  }
}

// ---------------- GEMM template (128x128 tile, BK=64, bf16 MFMA) ----------------
template<int EPI, int NSPLIT>
__global__ __launch_bounds__(256) void k_gemm(
    const unsigned short* __restrict__ Ag, int lda, int K,
    const unsigned short* __restrict__ Btg,
    const int* __restrict__ list, const int* __restrict__ offs, const int* __restrict__ cnt,
    unsigned short* __restrict__ pout,
    const float* __restrict__ W3s, float* __restrict__ pacc)
{
  __shared__ alignas(16) char smem[32768];
  const int NV = 4 * NSPLIT;
  int b = blockIdx.x;
  int y = (b & 7) + 8 * (b / (8 * NV));
  int v = (b >> 3) % NV;
  int x = v & 3, kh = v >> 2;

  int s = 0, t = y;
  for (; s < 4; s++){
    int nts = (cnt[s] + 127) >> 7;
    if (t < nts) break;
    t -= nts;
  }
  if (s >= 4) return;
  int cntS = cnt[s], offS = offs[s];
  int rt = t, n0 = x * 128;
  int tid = threadIdx.x, w = tid >> 6, lane = tid & 63;
  int wr = w >> 1, wc = w & 1;

  const unsigned short* Bts = Btg + (size_t)s * 512 * K;
  const unsigned short* gA[4];
  const unsigned short* gB[4];
  char* lA[4];
  char* lB[4];
  #pragma unroll
  for (int it = 0; it < 4; it++){
    int g = it * 4 + w;
    int idx = g * 64 + lane;
    int row = idx >> 3, ch = idx & 7;
    int cg = ch ^ (row & 7);
    int gr = rt * 128 + row; gr = gr < cntS ? gr : cntS - 1;
    int atom = list[offS + gr];
    gA[it] = Ag + (size_t)atom * lda + cg * 8;
    lA[it] = smem + g * 1024;
    gB[it] = Bts + (size_t)(n0 + row) * K + cg * 8;
    lB[it] = smem + 16384 + g * 1024;
  }

  int hi = lane >> 4, lo = lane & 15;
  f32x4 acc[4][4];
  #pragma unroll
  for (int mi = 0; mi < 4; mi++)
    #pragma unroll
    for (int ni = 0; ni < 4; ni++)
      #pragma unroll
      for (int r = 0; r < 4; r++) acc[mi][ni][r] = 0.f;

  int abase[4], a7[4], bbase[4], b7[4];
  #pragma unroll
  for (int mi = 0; mi < 4; mi++){ int row = wr*64 + mi*16 + lo; abase[mi] = row*128; a7[mi] = row & 7; }
  #pragma unroll
  for (int ni = 0; ni < 4; ni++){ int row = wc*64 + ni*16 + lo; bbase[ni] = 16384 + row*128; b7[ni] = row & 7; }

  int nk = K / 64;
  int k0 = ((nk * kh) / NSPLIT) * 64;
  int k1 = ((nk * (kh + 1)) / NSPLIT) * 64;

  for (int kt = k0; kt < k1; kt += 64){
    #pragma unroll
    for (int it = 0; it < 4; it++) gload16(gA[it] + kt, lA[it]);
    #pragma unroll
    for (int it = 0; it < 4; it++) gload16(gB[it] + kt, lB[it]);
    __syncthreads();
    #pragma unroll
    for (int kk = 0; kk < 2; kk++){
      bf16x8 af[4], bfr[4];
      #pragma unroll
      for (int mi = 0; mi < 4; mi++)
        af[mi] = *(const bf16x8*)(smem + abase[mi] + (((kk*4 + hi) ^ a7[mi]) << 4));
      #pragma unroll
      for (int ni = 0; ni < 4; ni++)
        bfr[ni] = *(const bf16x8*)(smem + bbase[ni] + (((kk*4 + hi) ^ b7[ni]) << 4));
      #pragma unroll
      for (int mi = 0; mi < 4; mi++)
        #pragma unroll
        for (int ni = 0; ni < 4; ni++)
          acc[mi][ni] = __builtin_amdgcn_mfma_f32_16x16x32_bf16(af[mi], bfr[ni], acc[mi][ni], 0, 0, 0);
    }
    __syncthreads();
  }

  int gn[4];
  #pragma unroll
  for (int ni = 0; ni < 4; ni++) gn[ni] = n0 + wc*64 + ni*16 + lo;

  if (EPI == 0){
    #pragma unroll
    for (int mi = 0; mi < 4; mi++){
      #pragma unroll
      for (int j = 0; j < 4; j++){
        int gr = rt*128 + wr*64 + mi*16 + hi*4 + j;
        if (gr < cntS){
          int atom = list[offS + gr];
          #pragma unroll
          for (int ni = 0; ni < 4; ni++)
            pout[((size_t)kh * NA + atom) * 512 + gn[ni]] = f2bf(acc[mi][ni][j]);
        }
      }
    }
  } else {
    float w3v[4];
    #pragma unroll
    for (int ni = 0; ni < 4; ni++) w3v[ni] = W3s[s * 512 + gn[ni]];
    float* pslot = pacc + (size_t)(x * 2 + wc) * NA;
    #pragma unroll
    for (int mi = 0; mi < 4; mi++){
      #pragma unroll
      for (int j = 0; j < 4; j++){
        int gr = rt*128 + wr*64 + mi*16 + hi*4 + j;
        if (gr < cntS){
          int atom = list[offS + gr];
          float pdot = 0.f;
          #pragma unroll
          for (int ni = 0; ni < 4; ni++)
            pdot += silu(acc[mi][ni][j]) * w3v[ni];
          pdot += __shfl_xor(pdot, 1, 16);
          pdot += __shfl_xor(pdot, 2, 16);
          pdot += __shfl_xor(pdot, 4, 16);
          pdot += __shfl_xor(pdot, 8, 16);
          if (lo == 0) pslot[atom] = pdot;
        }
      }
    }
  }
}

// ---------------- epilogue: combine 2 split-K partials + LN-affine + silu -> h1 -------
__global__ __launch_bounds__(256) void k_epi(
    const unsigned short* __restrict__ pbuf, const float* __restrict__ stats,
    const float* __restrict__ gW, const float* __restrict__ bW,
    const int* __restrict__ numbers, unsigned short* __restrict__ h1)
{
  int w = threadIdx.x >> 6, lane = threadIdx.x & 63;
  int atom = blockIdx.x * 4 + w;
  int s = numbers[atom];
  float mean = stats[2*atom], rstd = stats[2*atom+1];
  int c0 = lane * 8;
  u16x8 a0 = *reinterpret_cast<const u16x8*>(pbuf + (size_t)atom * 512 + c0);
  u16x8 a1 = *reinterpret_cast<const u16x8*>(pbuf + (size_t)(NA + atom) * 512 + c0);
  unsigned short o[8];
  #pragma unroll
  for (int j = 0; j < 8; j++){
    int c = c0 + j;
    float acc = bf2f(a0[j]) + bf2f(a1[j]);
    float vv = rstd * acc + bW[s*512 + c] - mean * rstd * gW[s*512 + c];
    o[j] = f2bf(silu(vv));
  }
  *reinterpret_cast<u16x8*>(h1 + (size_t)atom * 512 + c0) = *(const u16x8*)o;
}

// ---------------- final: sum 8 pacc partials/atom, wave-uniform molecule atomic -------
__global__ __launch_bounds__(256) void k_final2(
    const float* __restrict__ pacc, const int* __restrict__ numbers,
    const int* __restrict__ batch, const float* __restrict__ Wc,
    float* __restrict__ molOut)
{
  int atom = blockIdx.x * 256 + threadIdx.x;
  int lane = threadIdx.x & 63;
  float sum = 0.f;
  #pragma unroll
  for (int p = 0; p < 8; p++) sum += pacc[(size_t)p * NA + atom];
  float val = sum * (1.f / 128.f) + Wc[numbers[atom]];
  int mol = batch[atom];
  int m0 = __shfl(mol, 0, 64);
  int m63 = __shfl(mol, 63, 64);
  if (m0 == m63){
    #pragma unroll
    for (int m = 32; m; m >>= 1) val += __shfl_xor(val, m, 64);
    if (lane == 0) atomic_add_f(&molOut[mol], val);
  } else {
    atomic_add_f(&molOut[mol], val);
  }
}

extern "C" void kernel_launch(void* const* d_in, const int* in_sizes, int n_in,
                              void* d_out, int out_size, void* d_ws, size_t ws_size,
                              hipStream_t stream)
{
  const float* pos     = (const float*)d_in[0];
  const float* cells   = (const float*)d_in[1];
  const int*   numbers = (const int*)d_in[2];
  const int*   ei      = (const int*)d_in[3];
  const float* eoff    = (const float*)d_in[4];
  const int*   batch   = (const int*)d_in[5];
  const float* U       = (const float*)d_in[6];
  const float* gamma   = (const float*)d_in[7];
  const float* beta    = (const float*)d_in[8];
  const float* W1      = (const float*)d_in[9];
  const float* W2      = (const float*)d_in[10];
  const float* W3      = (const float*)d_in[11];
  const float* Wc      = (const float*)d_in[12];
  float* out = (float*)d_out;

  char* ws = (char*)d_ws;
  size_t off = 0;
  auto alloc = [&](size_t bytes) -> void* {
    void* p = ws + off;
    off += (bytes + 255) & ~(size_t)255;
    return p;
  };
  unsigned short* ps   = (unsigned short*)alloc((size_t)NA * FR * 2);      // 88 MB
  unsigned short* pbuf = (unsigned short*)alloc((size_t)2 * NA * 512 * 2); // 32 MB
  float* stats         = (float*)alloc((size_t)NA * 2 * 4);
  unsigned short* Wg1  = (unsigned short*)alloc((size_t)4 * 512 * FR * 2); // 11 MB
  unsigned short* W2t  = (unsigned short*)alloc((size_t)4 * 512 * 512 * 2);
  float* W3s           = (float*)alloc(4 * 512 * 4);
  unsigned short* h1   = (unsigned short*)alloc((size_t)NA * 512 * 2);
  float* pacc          = (float*)alloc((size_t)8 * NA * 4);
  int* list            = (int*)alloc(NA * 4);
  float* epack         = (float*)alloc((size_t)NE * 4 * 4);                // 8 MB
  int* startsK         = (int*)alloc((65536 + 1) * 4);
  // contiguous zero-init region: cnt64k + gW + bW (one memset)
  int* cnt64k          = (int*)alloc(65536 * 4);
  float* gW            = (float*)alloc(4 * 512 * 4);
  float* bW            = (float*)alloc(4 * 512 * 4);
  int* cursor64k       = (int*)alloc(65536 * 4);
  int* bsum            = (int*)alloc(256 * 4);
  int* boff            = (int*)alloc(256 * 4);
  int* bhist           = (int*)alloc(64 * 4 * 4);
  int* boffs           = (int*)alloc(64 * 4 * 4);
  int* ints            = (int*)alloc(64);
  int* cnt = ints; int* offs = ints + 8;

  hipMemsetAsync(cnt64k, 0, 65536 * 4 + 2 * 4 * 512 * 4, stream);
  hipMemsetAsync(out, 0, (size_t)out_size * 4, stream);

  // edge hist (by recv*4+species) + atom hist, fused
  k_hist<<<2048 + 64, 256, 0, stream>>>(ei, numbers, cnt64k, bhist);
  k_scanA<<<256, 256, 0, stream>>>(cnt64k, bsum);
  k_scanB<<<1, 256, 0, stream>>>(bsum, boff, startsK, bhist, boffs, ints);
  k_scanC<<<256, 256, 0, stream>>>(cnt64k, boff, startsK, cursor64k);
  k_sortpack<<<NE / 256, 256, 0, stream>>>(ei, numbers, eoff, cells, batch, pos,
                                           cursor64k, epack);
  k_aplace<<<NA / 256, 256, 0, stream>>>(numbers, boffs, list);

  // fused per-atom pipeline (streaming rvec, 6-wave ps, Gram stats)
  k_atom<<<NA, 384, 0, stream>>>(epack, startsK, U, ps, stats);

  // weight prep (single pass over W1; W2 mix + W3 mix fused)
  k_wg3<<<dim3(8, 42), 256, 0, stream>>>(W1, U, gamma, beta, Wg1, gW, bW);
  k_w2t<<<dim3(8, 8, 4), 256, 0, stream>>>(W2, U, W2t, W3, W3s);

  // GEMM1 split-K=2 (K=2688, 1088 blocks), then LN+silu epilogue
  k_gemm<0, 2><<<1088, 256, 0, stream>>>(ps, FR, FR, Wg1, list, offs, cnt,
                                         pbuf, nullptr, nullptr);
  k_epi<<<NA / 4, 256, 0, stream>>>(pbuf, stats, gW, bW, numbers, h1);

  // GEMM2 with fused silu + W3 dot -> per-atom partials (atomic-free)
  k_gemm<2, 1><<<544, 256, 0, stream>>>(h1, 512, 512, W2t, list, offs, cnt,
                                        nullptr, W3s, pacc);
  k_final2<<<NA / 256, 256, 0, stream>>>(pacc, numbers, batch, Wc, out);
}